// Round 2
// baseline (955.770 us; speedup 1.0000x reference)
//
#include <hip/hip_runtime.h>
#include <stdint.h>

#define N_NODES 20000
#define N_EDGES 320000
#define C 128
#define H 8
#define D 16

typedef short s16x8 __attribute__((ext_vector_type(8)));
typedef float f32x4 __attribute__((ext_vector_type(4)));

__device__ __forceinline__ unsigned short f2bf(float f) {
    unsigned int b = __float_as_uint(f);
    b += 0x7fffu + ((b >> 16) & 1u);
    return (unsigned short)(b >> 16);
}
__device__ __forceinline__ float bf2f(unsigned int u) {
    return __uint_as_float(u << 16);
}

// ---------------- utility ----------------
__global__ void zero_f32(float* p, int n) {
    int i = blockIdx.x * 256 + threadIdx.x;
    if (i < n) p[i] = 0.f;
}

__global__ void cvt_h(const float* ha, const float* hb, unsigned short* oa, unsigned short* ob) {
    int i = blockIdx.x * 256 + threadIdx.x;
    if (i < N_NODES * C) { oa[i] = f2bf(ha[i]); ob[i] = f2bf(hb[i]); }
}

// transpose-pack Wq and Wa to [type][out][in] bf16 for B-fragment loads
__global__ void pack_wt(const float* Wq, const float* Wa, unsigned short* Wqt, unsigned short* Wat) {
    int b = blockIdx.x;          // 2*128 blocks
    int t = b >> 7, n = b & 127;
    int i = threadIdx.x;         // 128 threads
    Wqt[(t * C + n) * C + i] = f2bf(Wq[(t * C + i) * C + n]);
    Wat[(t * C + n) * C + i] = f2bf(Wa[(t * C + i) * C + n]);
}

// fused relation weights: W~k[r] = Wk[type] @ blockdiag(att[r]), stored transposed bf16
__global__ void fuse_w(const float* Wk, const float* Wv, const float* bk, const float* bv,
                       const float* att, const float* msg,
                       unsigned short* Wkt, unsigned short* Wvt, float* bkt, float* bvt) {
    int r = blockIdx.x >> 3, h = blockIdx.x & 7;   // 32 blocks
    int t = r >> 1;                                 // src type: aa,ab from a; ba,bb from b
    __shared__ float sa[D * D], sm[D * D];
    int tid = threadIdx.x;
    if (tid < D * D) {
        sa[tid] = att[(r * H + h) * D * D + tid];
        sm[tid] = msg[(r * H + h) * D * D + tid];
    }
    __syncthreads();
    int i = tid & 127;
    for (int e = (tid >> 7); e < D; e += 2) {
        float sk = 0.f, sv = 0.f;
        for (int d = 0; d < D; ++d) {
            sk += Wk[(t * C + i) * C + h * D + d] * sa[d * D + e];
            sv += Wv[(t * C + i) * C + h * D + d] * sm[d * D + e];
        }
        Wkt[(r * C + h * D + e) * C + i] = f2bf(sk);
        Wvt[(r * C + h * D + e) * C + i] = f2bf(sv);
    }
    if (tid < D) {
        int e = tid;
        float sk = 0.f, sv = 0.f;
        for (int d = 0; d < D; ++d) {
            sk += bk[t * C + h * D + d] * sa[d * D + e];
            sv += bv[t * C + h * D + d] * sm[d * D + e];
        }
        bkt[r * C + h * D + e] = sk;
        bvt[r * C + h * D + e] = sv;
    }
}

// ---------------- MFMA projection: Out(bf16)[M,128] = A(bf16)[M,128] @ W + bias ----------------
// W passed transposed [out][in] bf16. Block: 256 thr = 4 waves, 64 rows/block.
__global__ __launch_bounds__(256) void proj_bf16(const unsigned short* __restrict__ A,
                                                 const unsigned short* __restrict__ Wt,
                                                 const float* __restrict__ bias,
                                                 unsigned short* __restrict__ Out, int M) {
    int wid = threadIdx.x >> 6, l = threadIdx.x & 63;
    int row_base = blockIdx.x * 64 + wid * 16;
    int lm = l & 15, q = l >> 4;
    f32x4 acc[8] = {};
    int arow = row_base + lm;
    if (arow >= M) arow = M - 1;
    const s16x8* Ap = (const s16x8*)(A + arow * C);
#pragma unroll
    for (int kc = 0; kc < 4; ++kc) {
        s16x8 af = Ap[kc * 4 + q];
#pragma unroll
        for (int t = 0; t < 8; ++t) {
            s16x8 bf = *(const s16x8*)(Wt + (t * 16 + lm) * C + kc * 32 + q * 8);
            acc[t] = __builtin_amdgcn_mfma_f32_16x16x32_bf16(af, bf, acc[t], 0, 0, 0);
        }
    }
#pragma unroll
    for (int t = 0; t < 8; ++t) {
        int col = t * 16 + lm;
        float b = bias[col];
#pragma unroll
        for (int i = 0; i < 4; ++i) {
            int row = row_base + q * 4 + i;
            if (row < M) Out[row * C + col] = f2bf(acc[t][i] + b);
        }
    }
}

// ---------------- final: out = al*(agg @ Wa + ba) + (1-al)*h ----------------
// NOTE: the 0.5 cross-reducer factor is applied ONCE, in node_k's agg write.
__global__ __launch_bounds__(256) void final_mm(const float* __restrict__ Agg,
                                                const unsigned short* __restrict__ Wat,
                                                const float* __restrict__ ba,
                                                const float* __restrict__ skip, int sidx,
                                                const float* __restrict__ h_orig,
                                                float* __restrict__ Out) {
    int wid = threadIdx.x >> 6, l = threadIdx.x & 63;
    int row_base = blockIdx.x * 64 + wid * 16;
    int lm = l & 15, q = l >> 4;
    f32x4 acc[8] = {};
    int arow = row_base + lm;
    if (arow >= N_NODES) arow = N_NODES - 1;
    const float* Ap = Agg + arow * C;
#pragma unroll
    for (int kc = 0; kc < 4; ++kc) {
        s16x8 af;
#pragma unroll
        for (int j = 0; j < 8; ++j) af[j] = (short)f2bf(Ap[kc * 32 + q * 8 + j]);
#pragma unroll
        for (int t = 0; t < 8; ++t) {
            s16x8 bf = *(const s16x8*)(Wat + (t * 16 + lm) * C + kc * 32 + q * 8);
            acc[t] = __builtin_amdgcn_mfma_f32_16x16x32_bf16(af, bf, acc[t], 0, 0, 0);
        }
    }
    float al = 1.f / (1.f + __expf(-skip[sidx]));
#pragma unroll
    for (int t = 0; t < 8; ++t) {
        int col = t * 16 + lm;
        float b = ba[col];
#pragma unroll
        for (int i = 0; i < 4; ++i) {
            int row = row_base + q * 4 + i;
            if (row < N_NODES)
                Out[row * C + col] = al * (acc[t][i] + b) + (1.f - al) * h_orig[row * C + col];
        }
    }
}

// ---------------- CSR build ----------------
__global__ void hist4(const int* d0, const int* d1, const int* d2, const int* d3, int* deg4) {
    int e = blockIdx.x * 256 + threadIdx.x;
    int r = blockIdx.y;
    const int* dd = (r == 0) ? d0 : (r == 1) ? d1 : (r == 2) ? d2 : d3;
    if (e < N_EDGES) atomicAdd(&deg4[r * N_NODES + dd[e]], 1);
}

__global__ __launch_bounds__(256) void scan4(const int* deg4, int* rowptr4, int* cursor4) {
    int r = blockIdx.x;
    const int* deg = deg4 + r * N_NODES;
    int* rp = rowptr4 + r * (N_NODES + 1);
    int* cur = cursor4 + r * N_NODES;
    int lane = threadIdx.x & 63, wid = threadIdx.x >> 6;
    __shared__ int wsum[4];
    int carry = 0;
    for (int base = 0; base < N_NODES; base += 256) {
        int i = base + threadIdx.x;
        int v = (i < N_NODES) ? deg[i] : 0;
        int incl = v;
#pragma unroll
        for (int off = 1; off < 64; off <<= 1) {
            int t = __shfl_up(incl, off);
            if (lane >= off) incl += t;
        }
        if (lane == 63) wsum[wid] = incl;
        __syncthreads();
        int woff = 0;
        for (int w = 0; w < wid; ++w) woff += wsum[w];
        int total = wsum[0] + wsum[1] + wsum[2] + wsum[3];
        int excl = carry + woff + incl - v;
        if (i < N_NODES) { rp[i] = excl; cur[i] = excl; }
        carry += total;
        __syncthreads();
    }
    if (threadIdx.x == 0) rp[N_NODES] = carry;
}

__global__ void fill4(const int* d0, const int* d1, const int* d2, const int* d3,
                      int* cursor4, int* eidx4) {
    int e = blockIdx.x * 256 + threadIdx.x;
    int r = blockIdx.y;
    const int* dd = (r == 0) ? d0 : (r == 1) ? d1 : (r == 2) ? d2 : d3;
    if (e < N_EDGES) {
        int pos = atomicAdd(&cursor4[r * N_NODES + dd[e]], 1);
        eidx4[r * N_EDGES + pos] = e;
    }
}

// ---------------- edge scores: wave per edge ----------------
__global__ __launch_bounds__(256) void score_k(const unsigned short* __restrict__ Q,
                                               const unsigned short* __restrict__ K,
                                               const int* __restrict__ src,
                                               const int* __restrict__ dst,
                                               const float* __restrict__ pri,
                                               float* __restrict__ score) {
    int wid = threadIdx.x >> 6, l = threadIdx.x & 63;
    const unsigned int* Q32 = (const unsigned int*)Q;
    const unsigned int* K32 = (const unsigned int*)K;
    int h = l >> 3;
    for (int e = blockIdx.x * 4 + wid; e < N_EDGES; e += 40000) {
        int s = src[e], d = dst[e];
        unsigned int qv = Q32[d * 64 + l];
        unsigned int kv = K32[s * 64 + l];
        float dot = bf2f(qv & 0xffffu) * bf2f(kv & 0xffffu) + bf2f(qv >> 16) * bf2f(kv >> 16);
#pragma unroll
        for (int m = 1; m < 8; m <<= 1) dot += __shfl_xor(dot, m);
        if ((l & 7) == 0) score[e * 8 + h] = dot * pri[h] * 0.25f;
    }
}

// ---------------- per-node softmax + aggregate: wave per node ----------------
__global__ __launch_bounds__(256) void node_k(const int* __restrict__ rowptr,
                                              const int* __restrict__ eidx,
                                              const int* __restrict__ src,
                                              const float* __restrict__ score,
                                              const unsigned short* __restrict__ V,
                                              float* __restrict__ agg) {
    int wid = threadIdx.x >> 6, l = threadIdx.x & 63;
    int n = blockIdx.x * 4 + wid;
    if (n >= N_NODES) return;
    int s0 = rowptr[n], s1 = rowptr[n + 1];
    if (s0 == s1) return;
    int h = l & 7, j = l >> 3;
    float m = -1e30f;
    for (int i = s0 + j; i < s1; i += 8) {
        int e = eidx[i];
        m = fmaxf(m, score[e * 8 + h]);
    }
#pragma unroll
    for (int mk = 8; mk < 64; mk <<= 1) m = fmaxf(m, __shfl_xor(m, mk));
    float ss = 0.f;
    for (int i = s0 + j; i < s1; i += 8) {
        int e = eidx[i];
        ss += __expf(score[e * 8 + h] - m);
    }
#pragma unroll
    for (int mk = 8; mk < 64; mk <<= 1) ss += __shfl_xor(ss, mk);
    float rs = 1.f / ss;
    int h2 = l >> 3;
    float m2 = __shfl(m, h2);
    float rs2 = __shfl(rs, h2);
    const unsigned int* V32 = (const unsigned int*)V;
    float ax = 0.f, ay = 0.f;
    for (int i = s0; i < s1; ++i) {
        int e = eidx[i];
        float w = __expf(score[e * 8 + h2] - m2) * rs2;
        int sv = src[e];
        unsigned int vv = V32[sv * 64 + l];
        ax += w * bf2f(vv & 0xffffu);
        ay += w * bf2f(vv >> 16);
    }
    float2* ap = (float2*)(agg + n * C + 2 * l);
    float2 old = *ap;
    old.x += 0.5f * ax;   // 0.5 = cross_reducer 'mean' over 2 relations (applied here ONLY)
    old.y += 0.5f * ay;
    *ap = old;
}

extern "C" void kernel_launch(void* const* d_in, const int* in_sizes, int n_in,
                              void* d_out, int out_size, void* d_ws, size_t ws_size,
                              hipStream_t stream) {
    const float* h_a  = (const float*)d_in[0];
    const float* h_b  = (const float*)d_in[1];
    const float* Wk   = (const float*)d_in[2];
    const float* bk   = (const float*)d_in[3];
    const float* Wq   = (const float*)d_in[4];
    const float* bq   = (const float*)d_in[5];
    const float* Wv   = (const float*)d_in[6];
    const float* bv   = (const float*)d_in[7];
    const float* Wa   = (const float*)d_in[8];
    const float* ba   = (const float*)d_in[9];
    const float* att  = (const float*)d_in[10];
    const float* msg  = (const float*)d_in[11];
    const float* pri  = (const float*)d_in[12];
    const float* skip = (const float*)d_in[13];
    const int* srcs[4] = {(const int*)d_in[14], (const int*)d_in[16], (const int*)d_in[18], (const int*)d_in[20]};
    const int* dsts[4] = {(const int*)d_in[15], (const int*)d_in[17], (const int*)d_in[19], (const int*)d_in[21]};
    float* out = (float*)d_out;

    char* w = (char*)d_ws;
    auto alloc = [&](size_t bytes) {
        char* p = w;
        w += (bytes + 255) & ~(size_t)255;
        return p;
    };
    unsigned short* ha_bf = (unsigned short*)alloc((size_t)N_NODES * C * 2);
    unsigned short* hb_bf = (unsigned short*)alloc((size_t)N_NODES * C * 2);
    unsigned short* Qa    = (unsigned short*)alloc((size_t)N_NODES * C * 2);
    unsigned short* Qb    = (unsigned short*)alloc((size_t)N_NODES * C * 2);
    unsigned short* Kb    = (unsigned short*)alloc((size_t)N_NODES * C * 2);
    unsigned short* Vb    = (unsigned short*)alloc((size_t)N_NODES * C * 2);
    unsigned short* Wqt   = (unsigned short*)alloc(2 * C * C * 2);
    unsigned short* Wat   = (unsigned short*)alloc(2 * C * C * 2);
    unsigned short* Wkt   = (unsigned short*)alloc(4 * C * C * 2);
    unsigned short* Wvt   = (unsigned short*)alloc(4 * C * C * 2);
    float* bkt            = (float*)alloc(4 * C * 4);
    float* bvt            = (float*)alloc(4 * C * 4);
    float* score          = (float*)alloc((size_t)N_EDGES * 8 * 4);
    int* deg4             = (int*)alloc(4 * N_NODES * 4);
    int* cursor4          = (int*)alloc(4 * N_NODES * 4);
    int* rowptr4          = (int*)alloc(4 * (N_NODES + 1) * 4);
    int* eidx4            = (int*)alloc((size_t)4 * N_EDGES * 4);
    float* agg            = (float*)alloc((size_t)2 * N_NODES * C * 4);
    float* agg_a = agg;
    float* agg_b = agg + (size_t)N_NODES * C;

    // init
    zero_f32<<<(2 * N_NODES * C + 255) / 256, 256, 0, stream>>>(agg, 2 * N_NODES * C);
    zero_f32<<<(4 * N_NODES + 255) / 256, 256, 0, stream>>>((float*)deg4, 4 * N_NODES);
    cvt_h<<<(N_NODES * C + 255) / 256, 256, 0, stream>>>(h_a, h_b, ha_bf, hb_bf);
    pack_wt<<<256, 128, 0, stream>>>(Wq, Wa, Wqt, Wat);
    fuse_w<<<32, 256, 0, stream>>>(Wk, Wv, bk, bv, att, msg, Wkt, Wvt, bkt, bvt);

    // CSR for all 4 relations
    hist4<<<dim3(1250, 4), 256, 0, stream>>>(dsts[0], dsts[1], dsts[2], dsts[3], deg4);
    scan4<<<4, 256, 0, stream>>>(deg4, rowptr4, cursor4);
    fill4<<<dim3(1250, 4), 256, 0, stream>>>(dsts[0], dsts[1], dsts[2], dsts[3], cursor4, eidx4);

    // Q projections (dst-type based)
    proj_bf16<<<313, 256, 0, stream>>>(ha_bf, Wqt, bq, Qa, N_NODES);
    proj_bf16<<<313, 256, 0, stream>>>(hb_bf, Wqt + C * C, bq + C, Qb, N_NODES);

    // relations: 0=aa 1=ab 2=ba 3=bb
    for (int r = 0; r < 4; ++r) {
        const unsigned short* hsrc = (r < 2) ? ha_bf : hb_bf;
        const unsigned short* Qd = (r == 0 || r == 2) ? Qa : Qb;
        float* aggd = (r == 0 || r == 2) ? agg_a : agg_b;
        proj_bf16<<<313, 256, 0, stream>>>(hsrc, Wkt + r * C * C, bkt + r * C, Kb, N_NODES);
        proj_bf16<<<313, 256, 0, stream>>>(hsrc, Wvt + r * C * C, bvt + r * C, Vb, N_NODES);
        score_k<<<10000, 256, 0, stream>>>(Qd, Kb, srcs[r], dsts[r], pri + r * 8, score);
        node_k<<<N_NODES / 4, 256, 0, stream>>>(rowptr4 + r * (N_NODES + 1), eidx4 + (size_t)r * N_EDGES,
                                                srcs[r], score, Vb, aggd);
    }

    // final skip-gated output
    final_mm<<<313, 256, 0, stream>>>(agg_a, Wat, ba, skip, 0, h_a, out);
    final_mm<<<313, 256, 0, stream>>>(agg_b, Wat + C * C, ba + C, skip, 1, h_b, out + (size_t)N_NODES * C);
}

// Round 3
// 670.837 us; speedup vs baseline: 1.4247x; 1.4247x over previous
//
#include <hip/hip_runtime.h>
#include <stdint.h>

#define N_NODES 20000
#define N_EDGES 320000
#define C 128
#define H 8
#define D 16

typedef short s16x8 __attribute__((ext_vector_type(8)));
typedef float f32x4 __attribute__((ext_vector_type(4)));

__device__ __forceinline__ unsigned short f2bf(float f) {
    unsigned int b = __float_as_uint(f);
    b += 0x7fffu + ((b >> 16) & 1u);
    return (unsigned short)(b >> 16);
}
__device__ __forceinline__ float bf2f(unsigned int u) {
    return __uint_as_float(u << 16);
}

// ---------------- utility ----------------
__global__ void zero_i32(int* p, int n) {
    int i = blockIdx.x * 256 + threadIdx.x;
    if (i < n) p[i] = 0;
}

__global__ void cvt_h(const float* ha, const float* hb, unsigned short* oa, unsigned short* ob) {
    int i = blockIdx.x * 256 + threadIdx.x;
    if (i < N_NODES * C) { oa[i] = f2bf(ha[i]); ob[i] = f2bf(hb[i]); }
}

// transpose-pack Wq and Wa to [type][out][in] bf16 for B-fragment loads
__global__ void pack_wt(const float* Wq, const float* Wa, unsigned short* Wqt, unsigned short* Wat) {
    int b = blockIdx.x;          // 2*128 blocks
    int t = b >> 7, n = b & 127;
    int i = threadIdx.x;         // 128 threads
    Wqt[(t * C + n) * C + i] = f2bf(Wq[(t * C + i) * C + n]);
    Wat[(t * C + n) * C + i] = f2bf(Wa[(t * C + i) * C + n]);
}

// fused relation weights: W~k[r] = Wk[type] @ blockdiag(att[r]), stored transposed bf16
__global__ void fuse_w(const float* Wk, const float* Wv, const float* bk, const float* bv,
                       const float* att, const float* msg,
                       unsigned short* Wkt, unsigned short* Wvt, float* bkt, float* bvt) {
    int r = blockIdx.x >> 3, h = blockIdx.x & 7;   // 32 blocks
    int t = r >> 1;                                 // src type: aa,ab from a; ba,bb from b
    __shared__ float sa[D * D], sm[D * D];
    int tid = threadIdx.x;
    if (tid < D * D) {
        sa[tid] = att[(r * H + h) * D * D + tid];
        sm[tid] = msg[(r * H + h) * D * D + tid];
    }
    __syncthreads();
    int i = tid & 127;
    for (int e = (tid >> 7); e < D; e += 2) {
        float sk = 0.f, sv = 0.f;
        for (int d = 0; d < D; ++d) {
            sk += Wk[(t * C + i) * C + h * D + d] * sa[d * D + e];
            sv += Wv[(t * C + i) * C + h * D + d] * sm[d * D + e];
        }
        Wkt[(r * C + h * D + e) * C + i] = f2bf(sk);
        Wvt[(r * C + h * D + e) * C + i] = f2bf(sv);
    }
    if (tid < D) {
        int e = tid;
        float sk = 0.f, sv = 0.f;
        for (int d = 0; d < D; ++d) {
            sk += bk[t * C + h * D + d] * sa[d * D + e];
            sv += bv[t * C + h * D + d] * sm[d * D + e];
        }
        bkt[r * C + h * D + e] = sk;
        bvt[r * C + h * D + e] = sv;
    }
}

// ---------------- fused MFMA projections: 10 jobs via blockIdx.y ----------------
// j=0,1: Q(a/b) = h @ Wq[t] + bq[t]; j=2..5: K[r]; j=6..9: V[r]
__global__ __launch_bounds__(256) void proj_all(const unsigned short* __restrict__ ha,
                                                const unsigned short* __restrict__ hb,
                                                const unsigned short* __restrict__ Wqt,
                                                const unsigned short* __restrict__ Wkt,
                                                const unsigned short* __restrict__ Wvt,
                                                const float* __restrict__ bq,
                                                const float* __restrict__ bkt,
                                                const float* __restrict__ bvt,
                                                unsigned short* __restrict__ Qa,
                                                unsigned short* __restrict__ Qb,
                                                unsigned short* __restrict__ Kall,
                                                unsigned short* __restrict__ Vall) {
    int j = blockIdx.y;
    const unsigned short* A;
    const unsigned short* Wt;
    const float* bias;
    unsigned short* Out;
    if (j < 2) {
        A = j ? hb : ha; Wt = Wqt + j * C * C; bias = bq + j * C; Out = j ? Qb : Qa;
    } else if (j < 6) {
        int r = j - 2;
        A = (r < 2) ? ha : hb; Wt = Wkt + r * C * C; bias = bkt + r * C;
        Out = Kall + (size_t)r * N_NODES * C;
    } else {
        int r = j - 6;
        A = (r < 2) ? ha : hb; Wt = Wvt + r * C * C; bias = bvt + r * C;
        Out = Vall + (size_t)r * N_NODES * C;
    }
    int wid = threadIdx.x >> 6, l = threadIdx.x & 63;
    int row_base = blockIdx.x * 64 + wid * 16;
    int lm = l & 15, q = l >> 4;
    f32x4 acc[8] = {};
    int arow = row_base + lm;
    if (arow >= N_NODES) arow = N_NODES - 1;
    const s16x8* Ap = (const s16x8*)(A + (size_t)arow * C);
#pragma unroll
    for (int kc = 0; kc < 4; ++kc) {
        s16x8 af = Ap[kc * 4 + q];
#pragma unroll
        for (int t = 0; t < 8; ++t) {
            s16x8 bf = *(const s16x8*)(Wt + (t * 16 + lm) * C + kc * 32 + q * 8);
            acc[t] = __builtin_amdgcn_mfma_f32_16x16x32_bf16(af, bf, acc[t], 0, 0, 0);
        }
    }
#pragma unroll
    for (int t = 0; t < 8; ++t) {
        int col = t * 16 + lm;
        float b = bias[col];
#pragma unroll
        for (int i = 0; i < 4; ++i) {
            int row = row_base + q * 4 + i;
            if (row < N_NODES) Out[(size_t)row * C + col] = f2bf(acc[t][i] + b);
        }
    }
}

// ---------------- final: out = al*(agg @ Wa + ba) + (1-al)*h ; agg is bf16 ----------------
__global__ __launch_bounds__(256) void final_mm(const unsigned short* __restrict__ Agg,
                                                const unsigned short* __restrict__ Wat,
                                                const float* __restrict__ ba,
                                                const float* __restrict__ skip, int sidx,
                                                const float* __restrict__ h_orig,
                                                float* __restrict__ Out) {
    int wid = threadIdx.x >> 6, l = threadIdx.x & 63;
    int row_base = blockIdx.x * 64 + wid * 16;
    int lm = l & 15, q = l >> 4;
    f32x4 acc[8] = {};
    int arow = row_base + lm;
    if (arow >= N_NODES) arow = N_NODES - 1;
    const s16x8* Ap = (const s16x8*)(Agg + (size_t)arow * C);
#pragma unroll
    for (int kc = 0; kc < 4; ++kc) {
        s16x8 af = Ap[kc * 4 + q];
#pragma unroll
        for (int t = 0; t < 8; ++t) {
            s16x8 bf = *(const s16x8*)(Wat + (t * 16 + lm) * C + kc * 32 + q * 8);
            acc[t] = __builtin_amdgcn_mfma_f32_16x16x32_bf16(af, bf, acc[t], 0, 0, 0);
        }
    }
    float al = 1.f / (1.f + __expf(-skip[sidx]));
#pragma unroll
    for (int t = 0; t < 8; ++t) {
        int col = t * 16 + lm;
        float b = ba[col];
#pragma unroll
        for (int i = 0; i < 4; ++i) {
            int row = row_base + q * 4 + i;
            if (row < N_NODES)
                Out[(size_t)row * C + col] = al * (acc[t][i] + b) + (1.f - al) * h_orig[(size_t)row * C + col];
        }
    }
}

// ---------------- CSR build ----------------
__global__ void hist4(const int* d0, const int* d1, const int* d2, const int* d3, int* deg4) {
    int e = blockIdx.x * 256 + threadIdx.x;
    int r = blockIdx.y;
    const int* dd = (r == 0) ? d0 : (r == 1) ? d1 : (r == 2) ? d2 : d3;
    if (e < N_EDGES) atomicAdd(&deg4[r * N_NODES + dd[e]], 1);
}

__global__ __launch_bounds__(256) void scan4(const int* deg4, int* rowptr4, int* cursor4) {
    int r = blockIdx.x;
    const int* deg = deg4 + r * N_NODES;
    int* rp = rowptr4 + r * (N_NODES + 1);
    int* cur = cursor4 + r * N_NODES;
    int lane = threadIdx.x & 63, wid = threadIdx.x >> 6;
    __shared__ int wsum[4];
    int carry = 0;
    for (int base = 0; base < N_NODES; base += 256) {
        int i = base + threadIdx.x;
        int v = (i < N_NODES) ? deg[i] : 0;
        int incl = v;
#pragma unroll
        for (int off = 1; off < 64; off <<= 1) {
            int t = __shfl_up(incl, off);
            if (lane >= off) incl += t;
        }
        if (lane == 63) wsum[wid] = incl;
        __syncthreads();
        int woff = 0;
        for (int w = 0; w < wid; ++w) woff += wsum[w];
        int total = wsum[0] + wsum[1] + wsum[2] + wsum[3];
        int excl = carry + woff + incl - v;
        if (i < N_NODES) { rp[i] = excl; cur[i] = excl; }
        carry += total;
        __syncthreads();
    }
    if (threadIdx.x == 0) rp[N_NODES] = carry;
}

// scatter src id (ushort payload) into dst-CSR slots
__global__ void fill4(const int* s0, const int* s1, const int* s2, const int* s3,
                      const int* d0, const int* d1, const int* d2, const int* d3,
                      int* cursor4, unsigned short* csrc4) {
    int e = blockIdx.x * 256 + threadIdx.x;
    int r = blockIdx.y;
    const int* dd = (r == 0) ? d0 : (r == 1) ? d1 : (r == 2) ? d2 : d3;
    const int* ss = (r == 0) ? s0 : (r == 1) ? s1 : (r == 2) ? s2 : s3;
    if (e < N_EDGES) {
        int pos = atomicAdd(&cursor4[r * N_NODES + dd[e]], 1);
        csrc4[(size_t)r * N_EDGES + pos] = (unsigned short)ss[e];
    }
}

// ---------------- fused per-node scoring + softmax + aggregate ----------------
// One wave per dst node; processes the TWO relations targeting this node type.
// Chunked (64-edge) online softmax; scores staged in per-wave LDS.
__global__ __launch_bounds__(256) void node2_k(const int* __restrict__ rpA,
                                               const unsigned short* __restrict__ csA,
                                               const unsigned int* __restrict__ KA,
                                               const unsigned int* __restrict__ VA,
                                               const float* __restrict__ priA,
                                               const int* __restrict__ rpB,
                                               const unsigned short* __restrict__ csB,
                                               const unsigned int* __restrict__ KB,
                                               const unsigned int* __restrict__ VB,
                                               const float* __restrict__ priB,
                                               const unsigned int* __restrict__ Q32,
                                               unsigned int* __restrict__ agg) {
    __shared__ float sc[4][512];
    int wid = threadIdx.x >> 6, l = threadIdx.x & 63;
    int n = blockIdx.x * 4 + wid;
    int hg = l >> 3;
    unsigned int qv = Q32[(size_t)n * 64 + l];
    float q0 = bf2f(qv & 0xffffu), q1 = bf2f(qv >> 16);
    float* mysc = sc[wid];
    float outx = 0.f, outy = 0.f;

#pragma unroll
    for (int rel = 0; rel < 2; ++rel) {
        const int* rp = rel ? rpB : rpA;
        const unsigned short* cs = rel ? csB : csA;
        const unsigned int* K32 = rel ? KB : KA;
        const unsigned int* V32 = rel ? VB : VA;
        float pv = (rel ? priB : priA)[hg] * 0.25f;
        int s0 = rp[n], s1 = rp[n + 1];
        float m = -1e30f, sum = 0.f;
        float ax0 = 0.f, ay0 = 0.f, ax1 = 0.f, ay1 = 0.f;
        for (int base = s0; base < s1; base += 64) {
            int cnt = min(64, s1 - base);
            // pass 1: score all edges of this chunk into LDS (loads pipeline freely)
            for (int i = 0; i < cnt; ++i) {
                int sv = cs[base + i];
                unsigned int kv = K32[(size_t)sv * 64 + l];
                float d = q0 * bf2f(kv & 0xffffu) + q1 * bf2f(kv >> 16);
                d += __shfl_xor(d, 1);
                d += __shfl_xor(d, 2);
                d += __shfl_xor(d, 4);
                if ((l & 7) == 0) mysc[i * 8 + hg] = d * pv;
            }
            // chunk max + rescale
            float mloc = -1e30f;
            for (int i = 0; i < cnt; ++i) mloc = fmaxf(mloc, mysc[i * 8 + hg]);
            float mnew = fmaxf(m, mloc);
            float alpha = __expf(m - mnew);   // first chunk: exp(-inf)=0, accs are 0
            sum *= alpha; ax0 *= alpha; ay0 *= alpha; ax1 *= alpha; ay1 *= alpha;
            m = mnew;
            // pass 2: weights + V gather (dual accumulators to break FMA chain)
            for (int i = 0; i < cnt; i += 2) {
                float w0 = __expf(mysc[i * 8 + hg] - m);
                sum += w0;
                int sv0 = cs[base + i];
                unsigned int vv0 = V32[(size_t)sv0 * 64 + l];
                ax0 += w0 * bf2f(vv0 & 0xffffu);
                ay0 += w0 * bf2f(vv0 >> 16);
                if (i + 1 < cnt) {
                    float w1 = __expf(mysc[(i + 1) * 8 + hg] - m);
                    sum += w1;
                    int sv1 = cs[base + i + 1];
                    unsigned int vv1 = V32[(size_t)sv1 * 64 + l];
                    ax1 += w1 * bf2f(vv1 & 0xffffu);
                    ay1 += w1 * bf2f(vv1 >> 16);
                }
            }
        }
        if (s1 > s0) {
            float rs = 1.f / sum;
            outx += (ax0 + ax1) * rs;
            outy += (ay0 + ay1) * rs;
        }
    }
    // 0.5 = cross_reducer 'mean'; agg stored bf16-packed
    unsigned int packed = (unsigned int)f2bf(0.5f * outx) | ((unsigned int)f2bf(0.5f * outy) << 16);
    agg[(size_t)n * 64 + l] = packed;
}

extern "C" void kernel_launch(void* const* d_in, const int* in_sizes, int n_in,
                              void* d_out, int out_size, void* d_ws, size_t ws_size,
                              hipStream_t stream) {
    const float* h_a  = (const float*)d_in[0];
    const float* h_b  = (const float*)d_in[1];
    const float* Wk   = (const float*)d_in[2];
    const float* bk   = (const float*)d_in[3];
    const float* Wq   = (const float*)d_in[4];
    const float* bq   = (const float*)d_in[5];
    const float* Wv   = (const float*)d_in[6];
    const float* bv   = (const float*)d_in[7];
    const float* Wa   = (const float*)d_in[8];
    const float* ba   = (const float*)d_in[9];
    const float* att  = (const float*)d_in[10];
    const float* msg  = (const float*)d_in[11];
    const float* pri  = (const float*)d_in[12];
    const float* skip = (const float*)d_in[13];
    const int* srcs[4] = {(const int*)d_in[14], (const int*)d_in[16], (const int*)d_in[18], (const int*)d_in[20]};
    const int* dsts[4] = {(const int*)d_in[15], (const int*)d_in[17], (const int*)d_in[19], (const int*)d_in[21]};
    float* out = (float*)d_out;

    char* w = (char*)d_ws;
    auto alloc = [&](size_t bytes) {
        char* p = w;
        w += (bytes + 255) & ~(size_t)255;
        return p;
    };
    unsigned short* ha_bf = (unsigned short*)alloc((size_t)N_NODES * C * 2);
    unsigned short* hb_bf = (unsigned short*)alloc((size_t)N_NODES * C * 2);
    unsigned short* Qa    = (unsigned short*)alloc((size_t)N_NODES * C * 2);
    unsigned short* Qb    = (unsigned short*)alloc((size_t)N_NODES * C * 2);
    unsigned short* Kall  = (unsigned short*)alloc((size_t)4 * N_NODES * C * 2);
    unsigned short* Vall  = (unsigned short*)alloc((size_t)4 * N_NODES * C * 2);
    unsigned short* Wqt   = (unsigned short*)alloc(2 * C * C * 2);
    unsigned short* Wat   = (unsigned short*)alloc(2 * C * C * 2);
    unsigned short* Wkt   = (unsigned short*)alloc(4 * C * C * 2);
    unsigned short* Wvt   = (unsigned short*)alloc(4 * C * C * 2);
    float* bkt            = (float*)alloc(4 * C * 4);
    float* bvt            = (float*)alloc(4 * C * 4);
    int* deg4             = (int*)alloc(4 * N_NODES * 4);
    int* cursor4          = (int*)alloc(4 * N_NODES * 4);
    int* rowptr4          = (int*)alloc(4 * (N_NODES + 1) * 4);
    unsigned short* csrc4 = (unsigned short*)alloc((size_t)4 * N_EDGES * 2);
    unsigned short* agg   = (unsigned short*)alloc((size_t)2 * N_NODES * C * 2);
    unsigned short* agg_a = agg;
    unsigned short* agg_b = agg + (size_t)N_NODES * C;

    // prep
    zero_i32<<<(4 * N_NODES + 255) / 256, 256, 0, stream>>>(deg4, 4 * N_NODES);
    cvt_h<<<(N_NODES * C + 255) / 256, 256, 0, stream>>>(h_a, h_b, ha_bf, hb_bf);
    pack_wt<<<256, 128, 0, stream>>>(Wq, Wa, Wqt, Wat);
    fuse_w<<<32, 256, 0, stream>>>(Wk, Wv, bk, bv, att, msg, Wkt, Wvt, bkt, bvt);

    // CSR for all 4 relations (payload = src as ushort)
    hist4<<<dim3(1250, 4), 256, 0, stream>>>(dsts[0], dsts[1], dsts[2], dsts[3], deg4);
    scan4<<<4, 256, 0, stream>>>(deg4, rowptr4, cursor4);
    fill4<<<dim3(1250, 4), 256, 0, stream>>>(srcs[0], srcs[1], srcs[2], srcs[3],
                                             dsts[0], dsts[1], dsts[2], dsts[3], cursor4, csrc4);

    // all 10 projections in one dispatch
    proj_all<<<dim3(313, 10), 256, 0, stream>>>(ha_bf, hb_bf, Wqt, Wkt, Wvt, bq, bkt, bvt,
                                                Qa, Qb, Kall, Vall);

    // fused scoring+softmax+aggregate: type a <- relations 0 (aa) and 2 (ba)
    node2_k<<<N_NODES / 4, 256, 0, stream>>>(
        rowptr4, csrc4, (const unsigned int*)Kall, (const unsigned int*)Vall, pri,
        rowptr4 + 2 * (N_NODES + 1), csrc4 + (size_t)2 * N_EDGES,
        (const unsigned int*)(Kall + (size_t)2 * N_NODES * C),
        (const unsigned int*)(Vall + (size_t)2 * N_NODES * C), pri + 16,
        (const unsigned int*)Qa, (unsigned int*)agg_a);
    // type b <- relations 1 (ab) and 3 (bb)
    node2_k<<<N_NODES / 4, 256, 0, stream>>>(
        rowptr4 + (N_NODES + 1), csrc4 + (size_t)N_EDGES,
        (const unsigned int*)(Kall + (size_t)N_NODES * C),
        (const unsigned int*)(Vall + (size_t)N_NODES * C), pri + 8,
        rowptr4 + 3 * (N_NODES + 1), csrc4 + (size_t)3 * N_EDGES,
        (const unsigned int*)(Kall + (size_t)3 * N_NODES * C),
        (const unsigned int*)(Vall + (size_t)3 * N_NODES * C), pri + 24,
        (const unsigned int*)Qb, (unsigned int*)agg_b);

    // final skip-gated output
    final_mm<<<313, 256, 0, stream>>>(agg_a, Wat, ba, skip, 0, h_a, out);
    final_mm<<<313, 256, 0, stream>>>(agg_b, Wat + C * C, ba + C, skip, 1, h_b, out + (size_t)N_NODES * C);
}

// Round 4
// 512.694 us; speedup vs baseline: 1.8642x; 1.3085x over previous
//
#include <hip/hip_runtime.h>
#include <stdint.h>

#define N_NODES 20000
#define N_EDGES 320000
#define C 128
#define H 8
#define D 16

typedef short s16x8 __attribute__((ext_vector_type(8)));
typedef float f32x4 __attribute__((ext_vector_type(4)));

__device__ __forceinline__ unsigned short f2bf(float f) {
    unsigned int b = __float_as_uint(f);
    b += 0x7fffu + ((b >> 16) & 1u);
    return (unsigned short)(b >> 16);
}
__device__ __forceinline__ float bf2f(unsigned int u) {
    return __uint_as_float(u << 16);
}

// ---------------- utility ----------------
__global__ void zero_i32(int* p, int n) {
    int i = blockIdx.x * 256 + threadIdx.x;
    if (i < n) p[i] = 0;
}

__global__ void cvt_h(const float* ha, const float* hb, unsigned short* oa, unsigned short* ob) {
    int i = blockIdx.x * 256 + threadIdx.x;
    if (i < N_NODES * C) { oa[i] = f2bf(ha[i]); ob[i] = f2bf(hb[i]); }
}

// transpose-pack Wq and Wa to [type][out][in] bf16 for B-fragment loads
__global__ void pack_wt(const float* Wq, const float* Wa, unsigned short* Wqt, unsigned short* Wat) {
    int b = blockIdx.x;          // 2*128 blocks
    int t = b >> 7, n = b & 127;
    int i = threadIdx.x;         // 128 threads
    Wqt[(t * C + n) * C + i] = f2bf(Wq[(t * C + i) * C + n]);
    Wat[(t * C + n) * C + i] = f2bf(Wa[(t * C + i) * C + n]);
}

// fused relation weights: W~k[r] = Wk[type] @ blockdiag(att[r]), stored transposed bf16
__global__ void fuse_w(const float* Wk, const float* Wv, const float* bk, const float* bv,
                       const float* att, const float* msg,
                       unsigned short* Wkt, unsigned short* Wvt, float* bkt, float* bvt) {
    int r = blockIdx.x >> 3, h = blockIdx.x & 7;   // 32 blocks
    int t = r >> 1;                                 // src type: aa,ab from a; ba,bb from b
    __shared__ float sa[D * D], sm[D * D];
    int tid = threadIdx.x;
    if (tid < D * D) {
        sa[tid] = att[(r * H + h) * D * D + tid];
        sm[tid] = msg[(r * H + h) * D * D + tid];
    }
    __syncthreads();
    int i = tid & 127;
    for (int e = (tid >> 7); e < D; e += 2) {
        float sk = 0.f, sv = 0.f;
        for (int d = 0; d < D; ++d) {
            sk += Wk[(t * C + i) * C + h * D + d] * sa[d * D + e];
            sv += Wv[(t * C + i) * C + h * D + d] * sm[d * D + e];
        }
        Wkt[(r * C + h * D + e) * C + i] = f2bf(sk);
        Wvt[(r * C + h * D + e) * C + i] = f2bf(sv);
    }
    if (tid < D) {
        int e = tid;
        float sk = 0.f, sv = 0.f;
        for (int d = 0; d < D; ++d) {
            sk += bk[t * C + h * D + d] * sa[d * D + e];
            sv += bv[t * C + h * D + d] * sm[d * D + e];
        }
        bkt[r * C + h * D + e] = sk;
        bvt[r * C + h * D + e] = sv;
    }
}

// ---------------- fused MFMA projections: 10 jobs via blockIdx.y ----------------
__global__ __launch_bounds__(256) void proj_all(const unsigned short* __restrict__ ha,
                                                const unsigned short* __restrict__ hb,
                                                const unsigned short* __restrict__ Wqt,
                                                const unsigned short* __restrict__ Wkt,
                                                const unsigned short* __restrict__ Wvt,
                                                const float* __restrict__ bq,
                                                const float* __restrict__ bkt,
                                                const float* __restrict__ bvt,
                                                unsigned short* __restrict__ Qa,
                                                unsigned short* __restrict__ Qb,
                                                unsigned short* __restrict__ Kall,
                                                unsigned short* __restrict__ Vall) {
    int j = blockIdx.y;
    const unsigned short* A;
    const unsigned short* Wt;
    const float* bias;
    unsigned short* Out;
    if (j < 2) {
        A = j ? hb : ha; Wt = Wqt + j * C * C; bias = bq + j * C; Out = j ? Qb : Qa;
    } else if (j < 6) {
        int r = j - 2;
        A = (r < 2) ? ha : hb; Wt = Wkt + r * C * C; bias = bkt + r * C;
        Out = Kall + (size_t)r * N_NODES * C;
    } else {
        int r = j - 6;
        A = (r < 2) ? ha : hb; Wt = Wvt + r * C * C; bias = bvt + r * C;
        Out = Vall + (size_t)r * N_NODES * C;
    }
    int wid = threadIdx.x >> 6, l = threadIdx.x & 63;
    int row_base = blockIdx.x * 64 + wid * 16;
    int lm = l & 15, q = l >> 4;
    f32x4 acc[8] = {};
    int arow = row_base + lm;
    if (arow >= N_NODES) arow = N_NODES - 1;
    const s16x8* Ap = (const s16x8*)(A + (size_t)arow * C);
#pragma unroll
    for (int kc = 0; kc < 4; ++kc) {
        s16x8 af = Ap[kc * 4 + q];
#pragma unroll
        for (int t = 0; t < 8; ++t) {
            s16x8 bf = *(const s16x8*)(Wt + (t * 16 + lm) * C + kc * 32 + q * 8);
            acc[t] = __builtin_amdgcn_mfma_f32_16x16x32_bf16(af, bf, acc[t], 0, 0, 0);
        }
    }
#pragma unroll
    for (int t = 0; t < 8; ++t) {
        int col = t * 16 + lm;
        float b = bias[col];
#pragma unroll
        for (int i = 0; i < 4; ++i) {
            int row = row_base + q * 4 + i;
            if (row < N_NODES) Out[(size_t)row * C + col] = f2bf(acc[t][i] + b);
        }
    }
}

// ---------------- final: out = al*(agg @ Wa + ba) + (1-al)*h ; agg is bf16 ----------------
__global__ __launch_bounds__(256) void final_mm(const unsigned short* __restrict__ Agg,
                                                const unsigned short* __restrict__ Wat,
                                                const float* __restrict__ ba,
                                                const float* __restrict__ skip, int sidx,
                                                const float* __restrict__ h_orig,
                                                float* __restrict__ Out) {
    int wid = threadIdx.x >> 6, l = threadIdx.x & 63;
    int row_base = blockIdx.x * 64 + wid * 16;
    int lm = l & 15, q = l >> 4;
    f32x4 acc[8] = {};
    int arow = row_base + lm;
    if (arow >= N_NODES) arow = N_NODES - 1;
    const s16x8* Ap = (const s16x8*)(Agg + (size_t)arow * C);
#pragma unroll
    for (int kc = 0; kc < 4; ++kc) {
        s16x8 af = Ap[kc * 4 + q];
#pragma unroll
        for (int t = 0; t < 8; ++t) {
            s16x8 bf = *(const s16x8*)(Wat + (t * 16 + lm) * C + kc * 32 + q * 8);
            acc[t] = __builtin_amdgcn_mfma_f32_16x16x32_bf16(af, bf, acc[t], 0, 0, 0);
        }
    }
    float al = 1.f / (1.f + __expf(-skip[sidx]));
#pragma unroll
    for (int t = 0; t < 8; ++t) {
        int col = t * 16 + lm;
        float b = ba[col];
#pragma unroll
        for (int i = 0; i < 4; ++i) {
            int row = row_base + q * 4 + i;
            if (row < N_NODES)
                Out[(size_t)row * C + col] = al * (acc[t][i] + b) + (1.f - al) * h_orig[(size_t)row * C + col];
        }
    }
}

// ---------------- CSR build (rank-recording; no atomic in fill) ----------------
__global__ void hist_rank(const int* d0, const int* d1, const int* d2, const int* d3,
                          int* deg4, unsigned short* rank4) {
    int e = blockIdx.x * 256 + threadIdx.x;
    int r = blockIdx.y;
    const int* dd = (r == 0) ? d0 : (r == 1) ? d1 : (r == 2) ? d2 : d3;
    if (e < N_EDGES) {
        int pos = atomicAdd(&deg4[r * N_NODES + dd[e]], 1);
        rank4[(size_t)r * N_EDGES + e] = (unsigned short)pos;
    }
}

__global__ __launch_bounds__(1024) void scan4(const int* deg4, int* rowptr4) {
    int r = blockIdx.x;
    const int* deg = deg4 + r * N_NODES;
    int* rp = rowptr4 + r * (N_NODES + 1);
    int lane = threadIdx.x & 63, wid = threadIdx.x >> 6;
    __shared__ int wsum[16];
    int carry = 0;
    for (int base = 0; base < N_NODES; base += 1024) {
        int i = base + threadIdx.x;
        int v = (i < N_NODES) ? deg[i] : 0;
        int incl = v;
#pragma unroll
        for (int off = 1; off < 64; off <<= 1) {
            int t = __shfl_up(incl, off);
            if (lane >= off) incl += t;
        }
        if (lane == 63) wsum[wid] = incl;
        __syncthreads();
        int woff = 0, total = 0;
#pragma unroll
        for (int w = 0; w < 16; ++w) {
            int s = wsum[w];
            woff += (w < wid) ? s : 0;
            total += s;
        }
        int excl = carry + woff + incl - v;
        if (i < N_NODES) rp[i] = excl;
        carry += total;
        __syncthreads();
    }
    if (threadIdx.x == 0) rp[N_NODES] = carry;
}

// scatter src id into CSR slot = rowptr[dst] + rank[e]  (no atomics)
__global__ void fill_nr(const int* s0, const int* s1, const int* s2, const int* s3,
                        const int* d0, const int* d1, const int* d2, const int* d3,
                        const int* rowptr4, const unsigned short* rank4,
                        unsigned short* csrc4) {
    int e = blockIdx.x * 256 + threadIdx.x;
    int r = blockIdx.y;
    const int* dd = (r == 0) ? d0 : (r == 1) ? d1 : (r == 2) ? d2 : d3;
    const int* ss = (r == 0) ? s0 : (r == 1) ? s1 : (r == 2) ? s2 : s3;
    if (e < N_EDGES) {
        int pos = rowptr4[r * (N_NODES + 1) + dd[e]] + rank4[(size_t)r * N_EDGES + e];
        csrc4[(size_t)r * N_EDGES + pos] = (unsigned short)ss[e];
    }
}

// ---------------- fused per-node scoring + softmax + aggregate ----------------
// One wave per dst node; two relations. Chunked (16-edge) online softmax.
// src ids preloaded coalesced into lane registers + __shfl broadcast, so all
// K/V gathers within a chunk are INDEPENDENT loads (pipelined, ~16 in flight).
__global__ __launch_bounds__(256) void node2_k(const int* __restrict__ rpA,
                                               const unsigned short* __restrict__ csA,
                                               const unsigned int* __restrict__ KA,
                                               const unsigned int* __restrict__ VA,
                                               const float* __restrict__ priA,
                                               const int* __restrict__ rpB,
                                               const unsigned short* __restrict__ csB,
                                               const unsigned int* __restrict__ KB,
                                               const unsigned int* __restrict__ VB,
                                               const float* __restrict__ priB,
                                               const unsigned int* __restrict__ Q32,
                                               unsigned int* __restrict__ agg) {
    int wid = threadIdx.x >> 6, l = threadIdx.x & 63;
    int n = blockIdx.x * 4 + wid;
    int hg = l >> 3;
    unsigned int qv = Q32[(size_t)n * 64 + l];
    float q0 = bf2f(qv & 0xffffu), q1 = bf2f(qv >> 16);
    float outx = 0.f, outy = 0.f;

#pragma unroll
    for (int rel = 0; rel < 2; ++rel) {
        const int* rp = rel ? rpB : rpA;
        const unsigned short* cs = rel ? csB : csA;
        const unsigned int* K32 = rel ? KB : KA;
        const unsigned int* V32 = rel ? VB : VA;
        float pv = (rel ? priB : priA)[hg] * 0.25f;
        int s0 = rp[n], s1 = rp[n + 1];
        float m = -1e30f, sum = 0.f;
        float ax0 = 0.f, ay0 = 0.f, ax1 = 0.f, ay1 = 0.f;
        for (int base = s0; base < s1; base += 16) {
            int cnt = s1 - base;
            if (cnt > 16) cnt = 16;
            int svl = 0;
            if (l < cnt) svl = cs[base + l];   // coalesced 2B preload
            float s[16];
#pragma unroll
            for (int i = 0; i < 16; ++i) {
                float d = -1e30f;
                if (i < cnt) {
                    int sv = __shfl(svl, i);   // register broadcast, no mem dep
                    unsigned int kv = K32[(size_t)sv * 64 + l];
                    d = q0 * bf2f(kv & 0xffffu) + q1 * bf2f(kv >> 16);
                    d += __shfl_xor(d, 1);
                    d += __shfl_xor(d, 2);
                    d += __shfl_xor(d, 4);     // full dot now in ALL 8 lanes of head group
                    d *= pv;
                }
                s[i] = d;
            }
            float mloc = s[0];
#pragma unroll
            for (int i = 1; i < 16; ++i) mloc = fmaxf(mloc, s[i]);
            float mnew = fmaxf(m, mloc);
            float alpha = __expf(m - mnew);    // first chunk: exp(-inf)=0
            sum *= alpha; ax0 *= alpha; ay0 *= alpha; ax1 *= alpha; ay1 *= alpha;
            m = mnew;
#pragma unroll
            for (int i = 0; i < 16; i += 2) {
                if (i < cnt) {
                    float w = __expf(s[i] - m);
                    sum += w;
                    int sv = __shfl(svl, i);
                    unsigned int vv = V32[(size_t)sv * 64 + l];
                    ax0 += w * bf2f(vv & 0xffffu);
                    ay0 += w * bf2f(vv >> 16);
                }
                if (i + 1 < cnt) {
                    float w = __expf(s[i + 1] - m);
                    sum += w;
                    int sv = __shfl(svl, i + 1);
                    unsigned int vv = V32[(size_t)sv * 64 + l];
                    ax1 += w * bf2f(vv & 0xffffu);
                    ay1 += w * bf2f(vv >> 16);
                }
            }
        }
        if (s1 > s0) {
            float rs = 1.f / sum;
            outx += (ax0 + ax1) * rs;
            outy += (ay0 + ay1) * rs;
        }
    }
    // 0.5 = cross_reducer 'mean'; agg stored bf16-packed
    unsigned int packed = (unsigned int)f2bf(0.5f * outx) | ((unsigned int)f2bf(0.5f * outy) << 16);
    agg[(size_t)n * 64 + l] = packed;
}

extern "C" void kernel_launch(void* const* d_in, const int* in_sizes, int n_in,
                              void* d_out, int out_size, void* d_ws, size_t ws_size,
                              hipStream_t stream) {
    const float* h_a  = (const float*)d_in[0];
    const float* h_b  = (const float*)d_in[1];
    const float* Wk   = (const float*)d_in[2];
    const float* bk   = (const float*)d_in[3];
    const float* Wq   = (const float*)d_in[4];
    const float* bq   = (const float*)d_in[5];
    const float* Wv   = (const float*)d_in[6];
    const float* bv   = (const float*)d_in[7];
    const float* Wa   = (const float*)d_in[8];
    const float* ba   = (const float*)d_in[9];
    const float* att  = (const float*)d_in[10];
    const float* msg  = (const float*)d_in[11];
    const float* pri  = (const float*)d_in[12];
    const float* skip = (const float*)d_in[13];
    const int* srcs[4] = {(const int*)d_in[14], (const int*)d_in[16], (const int*)d_in[18], (const int*)d_in[20]};
    const int* dsts[4] = {(const int*)d_in[15], (const int*)d_in[17], (const int*)d_in[19], (const int*)d_in[21]};
    float* out = (float*)d_out;

    char* w = (char*)d_ws;
    auto alloc = [&](size_t bytes) {
        char* p = w;
        w += (bytes + 255) & ~(size_t)255;
        return p;
    };
    unsigned short* ha_bf = (unsigned short*)alloc((size_t)N_NODES * C * 2);
    unsigned short* hb_bf = (unsigned short*)alloc((size_t)N_NODES * C * 2);
    unsigned short* Qa    = (unsigned short*)alloc((size_t)N_NODES * C * 2);
    unsigned short* Qb    = (unsigned short*)alloc((size_t)N_NODES * C * 2);
    unsigned short* Kall  = (unsigned short*)alloc((size_t)4 * N_NODES * C * 2);
    unsigned short* Vall  = (unsigned short*)alloc((size_t)4 * N_NODES * C * 2);
    unsigned short* Wqt   = (unsigned short*)alloc(2 * C * C * 2);
    unsigned short* Wat   = (unsigned short*)alloc(2 * C * C * 2);
    unsigned short* Wkt   = (unsigned short*)alloc(4 * C * C * 2);
    unsigned short* Wvt   = (unsigned short*)alloc(4 * C * C * 2);
    float* bkt            = (float*)alloc(4 * C * 4);
    float* bvt            = (float*)alloc(4 * C * 4);
    int* deg4             = (int*)alloc(4 * N_NODES * 4);
    int* rowptr4          = (int*)alloc(4 * (N_NODES + 1) * 4);
    unsigned short* rank4 = (unsigned short*)alloc((size_t)4 * N_EDGES * 2);
    unsigned short* csrc4 = (unsigned short*)alloc((size_t)4 * N_EDGES * 2);
    unsigned short* agg   = (unsigned short*)alloc((size_t)2 * N_NODES * C * 2);
    unsigned short* agg_a = agg;
    unsigned short* agg_b = agg + (size_t)N_NODES * C;

    // prep
    zero_i32<<<(4 * N_NODES + 255) / 256, 256, 0, stream>>>(deg4, 4 * N_NODES);
    cvt_h<<<(N_NODES * C + 255) / 256, 256, 0, stream>>>(h_a, h_b, ha_bf, hb_bf);
    pack_wt<<<256, 128, 0, stream>>>(Wq, Wa, Wqt, Wat);
    fuse_w<<<32, 256, 0, stream>>>(Wk, Wv, bk, bv, att, msg, Wkt, Wvt, bkt, bvt);

    // CSR for all 4 relations (payload = src as ushort)
    hist_rank<<<dim3(1250, 4), 256, 0, stream>>>(dsts[0], dsts[1], dsts[2], dsts[3], deg4, rank4);
    scan4<<<4, 1024, 0, stream>>>(deg4, rowptr4);
    fill_nr<<<dim3(1250, 4), 256, 0, stream>>>(srcs[0], srcs[1], srcs[2], srcs[3],
                                               dsts[0], dsts[1], dsts[2], dsts[3],
                                               rowptr4, rank4, csrc4);

    // all 10 projections in one dispatch
    proj_all<<<dim3(313, 10), 256, 0, stream>>>(ha_bf, hb_bf, Wqt, Wkt, Wvt, bq, bkt, bvt,
                                                Qa, Qb, Kall, Vall);

    // fused scoring+softmax+aggregate: type a <- relations 0 (aa) and 2 (ba)
    node2_k<<<N_NODES / 4, 256, 0, stream>>>(
        rowptr4, csrc4, (const unsigned int*)Kall, (const unsigned int*)Vall, pri,
        rowptr4 + 2 * (N_NODES + 1), csrc4 + (size_t)2 * N_EDGES,
        (const unsigned int*)(Kall + (size_t)2 * N_NODES * C),
        (const unsigned int*)(Vall + (size_t)2 * N_NODES * C), pri + 16,
        (const unsigned int*)Qa, (unsigned int*)agg_a);
    // type b <- relations 1 (ab) and 3 (bb)
    node2_k<<<N_NODES / 4, 256, 0, stream>>>(
        rowptr4 + (N_NODES + 1), csrc4 + (size_t)N_EDGES,
        (const unsigned int*)(Kall + (size_t)N_NODES * C),
        (const unsigned int*)(Vall + (size_t)N_NODES * C), pri + 8,
        rowptr4 + 3 * (N_NODES + 1), csrc4 + (size_t)3 * N_EDGES,
        (const unsigned int*)(Kall + (size_t)3 * N_NODES * C),
        (const unsigned int*)(Vall + (size_t)3 * N_NODES * C), pri + 24,
        (const unsigned int*)Qb, (unsigned int*)agg_b);

    // final skip-gated output
    final_mm<<<313, 256, 0, stream>>>(agg_a, Wat, ba, skip, 0, h_a, out);
    final_mm<<<313, 256, 0, stream>>>(agg_b, Wat + C * C, ba + C, skip, 1, h_b, out + (size_t)N_NODES * C);
}

// Round 5
// 449.709 us; speedup vs baseline: 2.1253x; 1.1401x over previous
//
#include <hip/hip_runtime.h>
#include <stdint.h>

#define N_NODES 20000
#define N_EDGES 320000
#define C 128
#define H 8
#define D 16
#define SLOT 64   // max degree per node per relation (Poisson(16); P(>=64)~1e-18, guarded)

typedef short s16x8 __attribute__((ext_vector_type(8)));
typedef float f32x4 __attribute__((ext_vector_type(4)));

__device__ __forceinline__ unsigned short f2bf(float f) {
    unsigned int b = __float_as_uint(f);
    b += 0x7fffu + ((b >> 16) & 1u);
    return (unsigned short)(b >> 16);
}
__device__ __forceinline__ float bf2f(unsigned int u) {
    return __uint_as_float(u << 16);
}

// ---------------- utility ----------------
__global__ void zero_i32(int* p, int n) {
    int i = blockIdx.x * 256 + threadIdx.x;
    if (i < n) p[i] = 0;
}

__global__ void cvt_h(const float* ha, const float* hb, unsigned short* oa, unsigned short* ob) {
    int i = blockIdx.x * 256 + threadIdx.x;
    if (i < N_NODES * C) { oa[i] = f2bf(ha[i]); ob[i] = f2bf(hb[i]); }
}

// transpose-pack Wq and Wa to [type][out][in] bf16 for B-fragment loads
__global__ void pack_wt(const float* Wq, const float* Wa, unsigned short* Wqt, unsigned short* Wat) {
    int b = blockIdx.x;          // 2*128 blocks
    int t = b >> 7, n = b & 127;
    int i = threadIdx.x;         // 128 threads
    Wqt[(t * C + n) * C + i] = f2bf(Wq[(t * C + i) * C + n]);
    Wat[(t * C + n) * C + i] = f2bf(Wa[(t * C + i) * C + n]);
}

// fused relation weights: W~k[r] = Wk[type] @ blockdiag(att[r]), stored transposed bf16
__global__ void fuse_w(const float* Wk, const float* Wv, const float* bk, const float* bv,
                       const float* att, const float* msg,
                       unsigned short* Wkt, unsigned short* Wvt, float* bkt, float* bvt) {
    int r = blockIdx.x >> 3, h = blockIdx.x & 7;   // 32 blocks
    int t = r >> 1;                                 // src type: aa,ab from a; ba,bb from b
    __shared__ float sa[D * D], sm[D * D];
    int tid = threadIdx.x;
    if (tid < D * D) {
        sa[tid] = att[(r * H + h) * D * D + tid];
        sm[tid] = msg[(r * H + h) * D * D + tid];
    }
    __syncthreads();
    int i = tid & 127;
    for (int e = (tid >> 7); e < D; e += 2) {
        float sk = 0.f, sv = 0.f;
        for (int d = 0; d < D; ++d) {
            sk += Wk[(t * C + i) * C + h * D + d] * sa[d * D + e];
            sv += Wv[(t * C + i) * C + h * D + d] * sm[d * D + e];
        }
        Wkt[(r * C + h * D + e) * C + i] = f2bf(sk);
        Wvt[(r * C + h * D + e) * C + i] = f2bf(sv);
    }
    if (tid < D) {
        int e = tid;
        float sk = 0.f, sv = 0.f;
        for (int d = 0; d < D; ++d) {
            sk += bk[t * C + h * D + d] * sa[d * D + e];
            sv += bv[t * C + h * D + d] * sm[d * D + e];
        }
        bkt[r * C + h * D + e] = sk;
        bvt[r * C + h * D + e] = sv;
    }
}

// ---------------- fused MFMA projections: 10 jobs via blockIdx.y ----------------
__global__ __launch_bounds__(256) void proj_all(const unsigned short* __restrict__ ha,
                                                const unsigned short* __restrict__ hb,
                                                const unsigned short* __restrict__ Wqt,
                                                const unsigned short* __restrict__ Wkt,
                                                const unsigned short* __restrict__ Wvt,
                                                const float* __restrict__ bq,
                                                const float* __restrict__ bkt,
                                                const float* __restrict__ bvt,
                                                unsigned short* __restrict__ Qa,
                                                unsigned short* __restrict__ Qb,
                                                unsigned short* __restrict__ Kall,
                                                unsigned short* __restrict__ Vall) {
    int j = blockIdx.y;
    const unsigned short* A;
    const unsigned short* Wt;
    const float* bias;
    unsigned short* Out;
    if (j < 2) {
        A = j ? hb : ha; Wt = Wqt + j * C * C; bias = bq + j * C; Out = j ? Qb : Qa;
    } else if (j < 6) {
        int r = j - 2;
        A = (r < 2) ? ha : hb; Wt = Wkt + r * C * C; bias = bkt + r * C;
        Out = Kall + (size_t)r * N_NODES * C;
    } else {
        int r = j - 6;
        A = (r < 2) ? ha : hb; Wt = Wvt + r * C * C; bias = bvt + r * C;
        Out = Vall + (size_t)r * N_NODES * C;
    }
    int wid = threadIdx.x >> 6, l = threadIdx.x & 63;
    int row_base = blockIdx.x * 64 + wid * 16;
    int lm = l & 15, q = l >> 4;
    f32x4 acc[8] = {};
    int arow = row_base + lm;
    if (arow >= N_NODES) arow = N_NODES - 1;
    const s16x8* Ap = (const s16x8*)(A + (size_t)arow * C);
#pragma unroll
    for (int kc = 0; kc < 4; ++kc) {
        s16x8 af = Ap[kc * 4 + q];
#pragma unroll
        for (int t = 0; t < 8; ++t) {
            s16x8 bf = *(const s16x8*)(Wt + (t * 16 + lm) * C + kc * 32 + q * 8);
            acc[t] = __builtin_amdgcn_mfma_f32_16x16x32_bf16(af, bf, acc[t], 0, 0, 0);
        }
    }
#pragma unroll
    for (int t = 0; t < 8; ++t) {
        int col = t * 16 + lm;
        float b = bias[col];
#pragma unroll
        for (int i = 0; i < 4; ++i) {
            int row = row_base + q * 4 + i;
            if (row < N_NODES) Out[(size_t)row * C + col] = f2bf(acc[t][i] + b);
        }
    }
}

// ---------------- final: out = al*(agg @ Wa + ba) + (1-al)*h ; agg is bf16 ----------------
__global__ __launch_bounds__(256) void final_mm(const unsigned short* __restrict__ Agg,
                                                const unsigned short* __restrict__ Wat,
                                                const float* __restrict__ ba,
                                                const float* __restrict__ skip, int sidx,
                                                const float* __restrict__ h_orig,
                                                float* __restrict__ Out) {
    int wid = threadIdx.x >> 6, l = threadIdx.x & 63;
    int row_base = blockIdx.x * 64 + wid * 16;
    int lm = l & 15, q = l >> 4;
    f32x4 acc[8] = {};
    int arow = row_base + lm;
    if (arow >= N_NODES) arow = N_NODES - 1;
    const s16x8* Ap = (const s16x8*)(Agg + (size_t)arow * C);
#pragma unroll
    for (int kc = 0; kc < 4; ++kc) {
        s16x8 af = Ap[kc * 4 + q];
#pragma unroll
        for (int t = 0; t < 8; ++t) {
            s16x8 bf = *(const s16x8*)(Wat + (t * 16 + lm) * C + kc * 32 + q * 8);
            acc[t] = __builtin_amdgcn_mfma_f32_16x16x32_bf16(af, bf, acc[t], 0, 0, 0);
        }
    }
    float al = 1.f / (1.f + __expf(-skip[sidx]));
#pragma unroll
    for (int t = 0; t < 8; ++t) {
        int col = t * 16 + lm;
        float b = ba[col];
#pragma unroll
        for (int i = 0; i < 4; ++i) {
            int row = row_base + q * 4 + i;
            if (row < N_NODES)
                Out[(size_t)row * C + col] = al * (acc[t][i] + b) + (1.f - al) * h_orig[(size_t)row * C + col];
        }
    }
}

// ---------------- one-shot bucket build (replaces hist+scan+fill) ----------------
// slots[r][d*SLOT + pos] = src ; deg[r][d] = count
__global__ void bucket_k(const int* s0, const int* s1, const int* s2, const int* s3,
                         const int* d0, const int* d1, const int* d2, const int* d3,
                         int* deg4, unsigned short* slots) {
    int e = blockIdx.x * 256 + threadIdx.x;
    int r = blockIdx.y;
    const int* dd = (r == 0) ? d0 : (r == 1) ? d1 : (r == 2) ? d2 : d3;
    const int* ss = (r == 0) ? s0 : (r == 1) ? s1 : (r == 2) ? s2 : s3;
    if (e < N_EDGES) {
        int d = dd[e];
        int pos = atomicAdd(&deg4[r * N_NODES + d], 1);
        if (pos < SLOT)
            slots[((size_t)r * N_NODES + d) * SLOT + pos] = (unsigned short)ss[e];
    }
}

// ---------------- fused per-node scoring + softmax + aggregate ----------------
// One wave per dst node; two relations. Chunked (16-edge) online softmax.
// src ids preloaded coalesced + __shfl broadcast; K AND V for the whole chunk
// loaded in ONE phase (V held packed in regs), so each chunk costs a single
// memory round-trip with 32 independent gathers in flight.
__global__ __launch_bounds__(256) void node2_k(const int* __restrict__ degA,
                                               const unsigned short* __restrict__ slA,
                                               const unsigned int* __restrict__ KA,
                                               const unsigned int* __restrict__ VA,
                                               const float* __restrict__ priA,
                                               const int* __restrict__ degB,
                                               const unsigned short* __restrict__ slB,
                                               const unsigned int* __restrict__ KB,
                                               const unsigned int* __restrict__ VB,
                                               const float* __restrict__ priB,
                                               const unsigned int* __restrict__ Q32,
                                               unsigned int* __restrict__ agg) {
    int wid = threadIdx.x >> 6, l = threadIdx.x & 63;
    int n = blockIdx.x * 4 + wid;
    int hg = l >> 3;
    unsigned int qv = Q32[(size_t)n * 64 + l];
    float q0 = bf2f(qv & 0xffffu), q1 = bf2f(qv >> 16);
    float outx = 0.f, outy = 0.f;

#pragma unroll
    for (int rel = 0; rel < 2; ++rel) {
        const unsigned short* cs = (rel ? slB : slA) + (size_t)n * SLOT;
        const unsigned int* K32 = rel ? KB : KA;
        const unsigned int* V32 = rel ? VB : VA;
        float pv = (rel ? priB : priA)[hg] * 0.25f;
        int deg = (rel ? degB : degA)[n];
        if (deg > SLOT) deg = SLOT;
        float m = -1e30f, sum = 0.f;
        float ax0 = 0.f, ay0 = 0.f, ax1 = 0.f, ay1 = 0.f;
        for (int base = 0; base < deg; base += 16) {
            int cnt = deg - base;
            if (cnt > 16) cnt = 16;
            int svl = 0;
            if (l < cnt) svl = cs[base + l];   // coalesced, 128B-aligned block
            float s[16];
            unsigned int vv[16];
#pragma unroll
            for (int i = 0; i < 16; ++i) {
                float d = -1e30f;
                unsigned int v = 0;
                if (i < cnt) {
                    int sv = __shfl(svl, i);   // register broadcast, no mem dep
                    unsigned int kv = K32[(size_t)sv * 64 + l];
                    v = V32[(size_t)sv * 64 + l];   // prefetched with K (indep of max)
                    d = q0 * bf2f(kv & 0xffffu) + q1 * bf2f(kv >> 16);
                    d += __shfl_xor(d, 1);
                    d += __shfl_xor(d, 2);
                    d += __shfl_xor(d, 4);     // full dot in all 8 lanes of head group
                    d *= pv;
                }
                s[i] = d;
                vv[i] = v;
            }
            float mloc = s[0];
#pragma unroll
            for (int i = 1; i < 16; ++i) mloc = fmaxf(mloc, s[i]);
            float mnew = fmaxf(m, mloc);
            float alpha = __expf(m - mnew);    // first chunk: exp(-inf)=0
            sum *= alpha; ax0 *= alpha; ay0 *= alpha; ax1 *= alpha; ay1 *= alpha;
            m = mnew;
#pragma unroll
            for (int i = 0; i < 16; i += 2) {
                if (i < cnt) {
                    float w = __expf(s[i] - m);
                    sum += w;
                    ax0 += w * bf2f(vv[i] & 0xffffu);
                    ay0 += w * bf2f(vv[i] >> 16);
                }
                if (i + 1 < cnt) {
                    float w = __expf(s[i + 1] - m);
                    sum += w;
                    ax1 += w * bf2f(vv[i + 1] & 0xffffu);
                    ay1 += w * bf2f(vv[i + 1] >> 16);
                }
            }
        }
        if (deg > 0) {
            float rs = 1.f / sum;
            outx += (ax0 + ax1) * rs;
            outy += (ay0 + ay1) * rs;
        }
    }
    // 0.5 = cross_reducer 'mean'; agg stored bf16-packed
    unsigned int packed = (unsigned int)f2bf(0.5f * outx) | ((unsigned int)f2bf(0.5f * outy) << 16);
    agg[(size_t)n * 64 + l] = packed;
}

extern "C" void kernel_launch(void* const* d_in, const int* in_sizes, int n_in,
                              void* d_out, int out_size, void* d_ws, size_t ws_size,
                              hipStream_t stream) {
    const float* h_a  = (const float*)d_in[0];
    const float* h_b  = (const float*)d_in[1];
    const float* Wk   = (const float*)d_in[2];
    const float* bk   = (const float*)d_in[3];
    const float* Wq   = (const float*)d_in[4];
    const float* bq   = (const float*)d_in[5];
    const float* Wv   = (const float*)d_in[6];
    const float* bv   = (const float*)d_in[7];
    const float* Wa   = (const float*)d_in[8];
    const float* ba   = (const float*)d_in[9];
    const float* att  = (const float*)d_in[10];
    const float* msg  = (const float*)d_in[11];
    const float* pri  = (const float*)d_in[12];
    const float* skip = (const float*)d_in[13];
    const int* srcs[4] = {(const int*)d_in[14], (const int*)d_in[16], (const int*)d_in[18], (const int*)d_in[20]};
    const int* dsts[4] = {(const int*)d_in[15], (const int*)d_in[17], (const int*)d_in[19], (const int*)d_in[21]};
    float* out = (float*)d_out;

    char* w = (char*)d_ws;
    auto alloc = [&](size_t bytes) {
        char* p = w;
        w += (bytes + 255) & ~(size_t)255;
        return p;
    };
    unsigned short* ha_bf = (unsigned short*)alloc((size_t)N_NODES * C * 2);
    unsigned short* hb_bf = (unsigned short*)alloc((size_t)N_NODES * C * 2);
    unsigned short* Qa    = (unsigned short*)alloc((size_t)N_NODES * C * 2);
    unsigned short* Qb    = (unsigned short*)alloc((size_t)N_NODES * C * 2);
    unsigned short* Kall  = (unsigned short*)alloc((size_t)4 * N_NODES * C * 2);
    unsigned short* Vall  = (unsigned short*)alloc((size_t)4 * N_NODES * C * 2);
    unsigned short* Wqt   = (unsigned short*)alloc(2 * C * C * 2);
    unsigned short* Wat   = (unsigned short*)alloc(2 * C * C * 2);
    unsigned short* Wkt   = (unsigned short*)alloc(4 * C * C * 2);
    unsigned short* Wvt   = (unsigned short*)alloc(4 * C * C * 2);
    float* bkt            = (float*)alloc(4 * C * 4);
    float* bvt            = (float*)alloc(4 * C * 4);
    int* deg4             = (int*)alloc(4 * N_NODES * 4);
    unsigned short* slots = (unsigned short*)alloc((size_t)4 * N_NODES * SLOT * 2);
    unsigned short* agg   = (unsigned short*)alloc((size_t)2 * N_NODES * C * 2);
    unsigned short* agg_a = agg;
    unsigned short* agg_b = agg + (size_t)N_NODES * C;

    // prep
    zero_i32<<<(4 * N_NODES + 255) / 256, 256, 0, stream>>>(deg4, 4 * N_NODES);
    cvt_h<<<(N_NODES * C + 255) / 256, 256, 0, stream>>>(h_a, h_b, ha_bf, hb_bf);
    pack_wt<<<256, 128, 0, stream>>>(Wq, Wa, Wqt, Wat);
    fuse_w<<<32, 256, 0, stream>>>(Wk, Wv, bk, bv, att, msg, Wkt, Wvt, bkt, bvt);

    // one-shot bucket build for all 4 relations
    bucket_k<<<dim3(1250, 4), 256, 0, stream>>>(srcs[0], srcs[1], srcs[2], srcs[3],
                                                dsts[0], dsts[1], dsts[2], dsts[3],
                                                deg4, slots);

    // all 10 projections in one dispatch
    proj_all<<<dim3(313, 10), 256, 0, stream>>>(ha_bf, hb_bf, Wqt, Wkt, Wvt, bq, bkt, bvt,
                                                Qa, Qb, Kall, Vall);

    // fused scoring+softmax+aggregate: type a <- relations 0 (aa) and 2 (ba)
    node2_k<<<N_NODES / 4, 256, 0, stream>>>(
        deg4, slots, (const unsigned int*)Kall, (const unsigned int*)Vall, pri,
        deg4 + 2 * N_NODES, slots + (size_t)2 * N_NODES * SLOT,
        (const unsigned int*)(Kall + (size_t)2 * N_NODES * C),
        (const unsigned int*)(Vall + (size_t)2 * N_NODES * C), pri + 16,
        (const unsigned int*)Qa, (unsigned int*)agg_a);
    // type b <- relations 1 (ab) and 3 (bb)
    node2_k<<<N_NODES / 4, 256, 0, stream>>>(
        deg4 + N_NODES, slots + (size_t)N_NODES * SLOT,
        (const unsigned int*)(Kall + (size_t)N_NODES * C),
        (const unsigned int*)(Vall + (size_t)N_NODES * C), pri + 8,
        deg4 + 3 * N_NODES, slots + (size_t)3 * N_NODES * SLOT,
        (const unsigned int*)(Kall + (size_t)3 * N_NODES * C),
        (const unsigned int*)(Vall + (size_t)3 * N_NODES * C), pri + 24,
        (const unsigned int*)Qb, (unsigned int*)agg_b);

    // final skip-gated output
    final_mm<<<313, 256, 0, stream>>>(agg_a, Wat, ba, skip, 0, h_a, out);
    final_mm<<<313, 256, 0, stream>>>(agg_b, Wat + C * C, ba + C, skip, 1, h_b, out + (size_t)N_NODES * C);
}

// Round 6
// 445.645 us; speedup vs baseline: 2.1447x; 1.0091x over previous
//
#include <hip/hip_runtime.h>
#include <stdint.h>

#define N_NODES 20000
#define N_EDGES 320000
#define C 128
#define H 8
#define D 16
#define SLOT 64      // max degree per node per relation (Poisson(16); P(>=64)~1e-18, guarded)
#define RANGES 625   // dst ranges of 32 nodes; 625*32 == 20000 exactly
#define CAP 768      // per-(relation,range) record capacity; mean 512, +11 sigma, guarded

typedef short s16x8 __attribute__((ext_vector_type(8)));
typedef float f32x4 __attribute__((ext_vector_type(4)));

__device__ __forceinline__ unsigned short f2bf(float f) {
    unsigned int b = __float_as_uint(f);
    b += 0x7fffu + ((b >> 16) & 1u);
    return (unsigned short)(b >> 16);
}
__device__ __forceinline__ float bf2f(unsigned int u) {
    return __uint_as_float(u << 16);
}

// ---------------- utility ----------------
__global__ void zero_i32(int* p, int n) {
    int i = blockIdx.x * 256 + threadIdx.x;
    if (i < n) p[i] = 0;
}

__global__ void cvt_h(const float* ha, const float* hb, unsigned short* oa, unsigned short* ob) {
    int i = blockIdx.x * 256 + threadIdx.x;
    if (i < N_NODES * C) { oa[i] = f2bf(ha[i]); ob[i] = f2bf(hb[i]); }
}

// transpose-pack Wq and Wa to [type][out][in] bf16 for B-fragment loads
__global__ void pack_wt(const float* Wq, const float* Wa, unsigned short* Wqt, unsigned short* Wat) {
    int b = blockIdx.x;          // 2*128 blocks
    int t = b >> 7, n = b & 127;
    int i = threadIdx.x;         // 128 threads
    Wqt[(t * C + n) * C + i] = f2bf(Wq[(t * C + i) * C + n]);
    Wat[(t * C + n) * C + i] = f2bf(Wa[(t * C + i) * C + n]);
}

// fused relation weights: W~k[r] = Wk[type] @ blockdiag(att[r]), stored transposed bf16
__global__ void fuse_w(const float* Wk, const float* Wv, const float* bk, const float* bv,
                       const float* att, const float* msg,
                       unsigned short* Wkt, unsigned short* Wvt, float* bkt, float* bvt) {
    int r = blockIdx.x >> 3, h = blockIdx.x & 7;   // 32 blocks
    int t = r >> 1;                                 // src type: aa,ab from a; ba,bb from b
    __shared__ float sa[D * D], sm[D * D];
    int tid = threadIdx.x;
    if (tid < D * D) {
        sa[tid] = att[(r * H + h) * D * D + tid];
        sm[tid] = msg[(r * H + h) * D * D + tid];
    }
    __syncthreads();
    int i = tid & 127;
    for (int e = (tid >> 7); e < D; e += 2) {
        float sk = 0.f, sv = 0.f;
        for (int d = 0; d < D; ++d) {
            sk += Wk[(t * C + i) * C + h * D + d] * sa[d * D + e];
            sv += Wv[(t * C + i) * C + h * D + d] * sm[d * D + e];
        }
        Wkt[(r * C + h * D + e) * C + i] = f2bf(sk);
        Wvt[(r * C + h * D + e) * C + i] = f2bf(sv);
    }
    if (tid < D) {
        int e = tid;
        float sk = 0.f, sv = 0.f;
        for (int d = 0; d < D; ++d) {
            sk += bk[t * C + h * D + d] * sa[d * D + e];
            sv += bv[t * C + h * D + d] * sm[d * D + e];
        }
        bkt[r * C + h * D + e] = sk;
        bvt[r * C + h * D + e] = sv;
    }
}

// ---------------- fused MFMA projections: 10 jobs via blockIdx.y ----------------
__global__ __launch_bounds__(256) void proj_all(const unsigned short* __restrict__ ha,
                                                const unsigned short* __restrict__ hb,
                                                const unsigned short* __restrict__ Wqt,
                                                const unsigned short* __restrict__ Wkt,
                                                const unsigned short* __restrict__ Wvt,
                                                const float* __restrict__ bq,
                                                const float* __restrict__ bkt,
                                                const float* __restrict__ bvt,
                                                unsigned short* __restrict__ Qa,
                                                unsigned short* __restrict__ Qb,
                                                unsigned short* __restrict__ Kall,
                                                unsigned short* __restrict__ Vall) {
    int j = blockIdx.y;
    const unsigned short* A;
    const unsigned short* Wt;
    const float* bias;
    unsigned short* Out;
    if (j < 2) {
        A = j ? hb : ha; Wt = Wqt + j * C * C; bias = bq + j * C; Out = j ? Qb : Qa;
    } else if (j < 6) {
        int r = j - 2;
        A = (r < 2) ? ha : hb; Wt = Wkt + r * C * C; bias = bkt + r * C;
        Out = Kall + (size_t)r * N_NODES * C;
    } else {
        int r = j - 6;
        A = (r < 2) ? ha : hb; Wt = Wvt + r * C * C; bias = bvt + r * C;
        Out = Vall + (size_t)r * N_NODES * C;
    }
    int wid = threadIdx.x >> 6, l = threadIdx.x & 63;
    int row_base = blockIdx.x * 64 + wid * 16;
    int lm = l & 15, q = l >> 4;
    f32x4 acc[8] = {};
    int arow = row_base + lm;
    if (arow >= N_NODES) arow = N_NODES - 1;
    const s16x8* Ap = (const s16x8*)(A + (size_t)arow * C);
#pragma unroll
    for (int kc = 0; kc < 4; ++kc) {
        s16x8 af = Ap[kc * 4 + q];
#pragma unroll
        for (int t = 0; t < 8; ++t) {
            s16x8 bf = *(const s16x8*)(Wt + (t * 16 + lm) * C + kc * 32 + q * 8);
            acc[t] = __builtin_amdgcn_mfma_f32_16x16x32_bf16(af, bf, acc[t], 0, 0, 0);
        }
    }
#pragma unroll
    for (int t = 0; t < 8; ++t) {
        int col = t * 16 + lm;
        float b = bias[col];
#pragma unroll
        for (int i = 0; i < 4; ++i) {
            int row = row_base + q * 4 + i;
            if (row < N_NODES) Out[(size_t)row * C + col] = f2bf(acc[t][i] + b);
        }
    }
}

// ---------------- final: out = al*(agg @ Wa + ba) + (1-al)*h ; both types via blockIdx.y ----------------
__global__ __launch_bounds__(256) void final_mm(const unsigned short* __restrict__ AggAll,
                                                const unsigned short* __restrict__ WatAll,
                                                const float* __restrict__ baAll,
                                                const float* __restrict__ skip,
                                                const float* __restrict__ h_a,
                                                const float* __restrict__ h_b,
                                                float* __restrict__ OutAll) {
    int ty = blockIdx.y;
    const unsigned short* Agg = AggAll + (size_t)ty * N_NODES * C;
    const unsigned short* Wat = WatAll + ty * C * C;
    const float* ba = baAll + ty * C;
    const float* h_orig = ty ? h_b : h_a;
    float* Out = OutAll + (size_t)ty * N_NODES * C;
    int wid = threadIdx.x >> 6, l = threadIdx.x & 63;
    int row_base = blockIdx.x * 64 + wid * 16;
    int lm = l & 15, q = l >> 4;
    f32x4 acc[8] = {};
    int arow = row_base + lm;
    if (arow >= N_NODES) arow = N_NODES - 1;
    const s16x8* Ap = (const s16x8*)(Agg + (size_t)arow * C);
#pragma unroll
    for (int kc = 0; kc < 4; ++kc) {
        s16x8 af = Ap[kc * 4 + q];
#pragma unroll
        for (int t = 0; t < 8; ++t) {
            s16x8 bf = *(const s16x8*)(Wat + (t * 16 + lm) * C + kc * 32 + q * 8);
            acc[t] = __builtin_amdgcn_mfma_f32_16x16x32_bf16(af, bf, acc[t], 0, 0, 0);
        }
    }
    float al = 1.f / (1.f + __expf(-skip[ty]));
#pragma unroll
    for (int t = 0; t < 8; ++t) {
        int col = t * 16 + lm;
        float b = ba[col];
#pragma unroll
        for (int i = 0; i < 4; ++i) {
            int row = row_base + q * 4 + i;
            if (row < N_NODES)
                Out[(size_t)row * C + col] = al * (acc[t][i] + b) + (1.f - al) * h_orig[(size_t)row * C + col];
        }
    }
}

// ---------------- P1: coarse partition into 625 dst-ranges per relation ----------------
// Writes per range are cursor-sequential -> frontier ~160 KB (L2-resident),
// killing bucket_k's 26x partial-line HBM write amplification.
__global__ void part_k(const int* s0, const int* s1, const int* s2, const int* s3,
                       const int* d0, const int* d1, const int* d2, const int* d3,
                       int* cur, unsigned int* part) {
    int e = blockIdx.x * 256 + threadIdx.x;
    int r = blockIdx.y;
    const int* dd = (r == 0) ? d0 : (r == 1) ? d1 : (r == 2) ? d2 : d3;
    const int* ss = (r == 0) ? s0 : (r == 1) ? s1 : (r == 2) ? s2 : s3;
    if (e < N_EDGES) {
        int d = dd[e];
        int range = d >> 5;
        int pos = atomicAdd(&cur[(r * RANGES + range) * 16], 1);   // stride 16: one cursor per 64B line
        if (pos < CAP)
            part[((size_t)(r * RANGES + range)) * CAP + pos] =
                (unsigned int)ss[e] | ((unsigned int)(d & 31) << 16);
    }
}

// ---------------- P2: LDS-bin + fused scoring/softmax/aggregate ----------------
// One block per (type, range-of-32-dsts). Bin the 2 relations' records into
// LDS slots, then each wave runs online softmax for 8 dsts, src ids served
// by LDS broadcast (same-address, conflict-free).
__global__ __launch_bounds__(256) void node_p2(const int* __restrict__ cur,
                                               const unsigned int* __restrict__ part,
                                               const unsigned int* __restrict__ Kall,
                                               const unsigned int* __restrict__ Vall,
                                               const float* __restrict__ pri,
                                               const unsigned int* __restrict__ Qa,
                                               const unsigned int* __restrict__ Qb,
                                               unsigned int* __restrict__ agg) {
    __shared__ unsigned short slot[2][32][SLOT];
    __shared__ int cnt[2][32];
    int g = blockIdx.x;
    int type = (g >= RANGES) ? 1 : 0;
    int range = g - type * RANGES;
    int relA = type ? 1 : 0;           // ab : aa
    int relB = type ? 3 : 2;           // bb : ba
    if (threadIdx.x < 64) cnt[threadIdx.x >> 5][threadIdx.x & 31] = 0;
    __syncthreads();
#pragma unroll
    for (int rr = 0; rr < 2; ++rr) {
        int rel = rr ? relB : relA;
        int c = cur[(rel * RANGES + range) * 16];
        if (c > CAP) c = CAP;
        const unsigned int* pp = part + ((size_t)(rel * RANGES + range)) * CAP;
        for (int i = threadIdx.x; i < c; i += 256) {
            unsigned int rec = pp[i];
            int dof = rec >> 16;
            int p = atomicAdd(&cnt[rr][dof], 1);
            if (p < SLOT) slot[rr][dof][p] = (unsigned short)(rec & 0xffffu);
        }
    }
    __syncthreads();

    int wid = threadIdx.x >> 6, l = threadIdx.x & 63;
    int hg = l >> 3;
    const unsigned int* Q32 = type ? Qb : Qa;
    const unsigned int* KArel = Kall + (size_t)relA * N_NODES * 64;
    const unsigned int* VArel = Vall + (size_t)relA * N_NODES * 64;
    const unsigned int* KBrel = Kall + (size_t)relB * N_NODES * 64;
    const unsigned int* VBrel = Vall + (size_t)relB * N_NODES * 64;
    float pvA = pri[relA * 8 + hg] * 0.25f;
    float pvB = pri[relB * 8 + hg] * 0.25f;

#pragma unroll 1
    for (int t = 0; t < 8; ++t) {
        int dof = wid * 8 + t;
        int n = range * 32 + dof;
        unsigned int qv = Q32[(size_t)n * 64 + l];
        float q0 = bf2f(qv & 0xffffu), q1 = bf2f(qv >> 16);
        float outx = 0.f, outy = 0.f;
#pragma unroll 1
        for (int rr = 0; rr < 2; ++rr) {
            const unsigned int* K32 = rr ? KBrel : KArel;
            const unsigned int* V32 = rr ? VBrel : VArel;
            float pv = rr ? pvB : pvA;
            int deg = cnt[rr][dof];
            if (deg > SLOT) deg = SLOT;
            float m = -1e30f, sum = 0.f;
            float ax0 = 0.f, ay0 = 0.f, ax1 = 0.f, ay1 = 0.f;
            for (int base = 0; base < deg; base += 16) {
                int cc = deg - base;
                if (cc > 16) cc = 16;
                float s[16];
                unsigned int vv[16];
#pragma unroll
                for (int i = 0; i < 16; ++i) {
                    float d = -1e30f;
                    unsigned int v = 0;
                    if (i < cc) {
                        int sv = slot[rr][dof][base + i];   // LDS broadcast
                        unsigned int kv = K32[(size_t)sv * 64 + l];
                        v = V32[(size_t)sv * 64 + l];       // fetched with K (indep of max)
                        d = q0 * bf2f(kv & 0xffffu) + q1 * bf2f(kv >> 16);
                        d += __shfl_xor(d, 1);
                        d += __shfl_xor(d, 2);
                        d += __shfl_xor(d, 4);              // full dot in all 8 lanes of head
                        d *= pv;
                    }
                    s[i] = d;
                    vv[i] = v;
                }
                float mloc = s[0];
#pragma unroll
                for (int i = 1; i < 16; ++i) mloc = fmaxf(mloc, s[i]);
                float mnew = fmaxf(m, mloc);
                float alpha = __expf(m - mnew);             // first chunk: exp(-inf)=0
                sum *= alpha; ax0 *= alpha; ay0 *= alpha; ax1 *= alpha; ay1 *= alpha;
                m = mnew;
#pragma unroll
                for (int i = 0; i < 16; i += 2) {
                    if (i < cc) {
                        float ww = __expf(s[i] - m);
                        sum += ww;
                        ax0 += ww * bf2f(vv[i] & 0xffffu);
                        ay0 += ww * bf2f(vv[i] >> 16);
                    }
                    if (i + 1 < cc) {
                        float ww = __expf(s[i + 1] - m);
                        sum += ww;
                        ax1 += ww * bf2f(vv[i + 1] & 0xffffu);
                        ay1 += ww * bf2f(vv[i + 1] >> 16);
                    }
                }
            }
            if (deg > 0) {
                float rs = 1.f / sum;
                outx += (ax0 + ax1) * rs;
                outy += (ay0 + ay1) * rs;
            }
        }
        // 0.5 = cross_reducer 'mean'; agg stored bf16-packed
        unsigned int packed = (unsigned int)f2bf(0.5f * outx) | ((unsigned int)f2bf(0.5f * outy) << 16);
        agg[((size_t)type * N_NODES + n) * 64 + l] = packed;
    }
}

extern "C" void kernel_launch(void* const* d_in, const int* in_sizes, int n_in,
                              void* d_out, int out_size, void* d_ws, size_t ws_size,
                              hipStream_t stream) {
    const float* h_a  = (const float*)d_in[0];
    const float* h_b  = (const float*)d_in[1];
    const float* Wk   = (const float*)d_in[2];
    const float* bk   = (const float*)d_in[3];
    const float* Wq   = (const float*)d_in[4];
    const float* bq   = (const float*)d_in[5];
    const float* Wv   = (const float*)d_in[6];
    const float* bv   = (const float*)d_in[7];
    const float* Wa   = (const float*)d_in[8];
    const float* ba   = (const float*)d_in[9];
    const float* att  = (const float*)d_in[10];
    const float* msg  = (const float*)d_in[11];
    const float* pri  = (const float*)d_in[12];
    const float* skip = (const float*)d_in[13];
    const int* srcs[4] = {(const int*)d_in[14], (const int*)d_in[16], (const int*)d_in[18], (const int*)d_in[20]};
    const int* dsts[4] = {(const int*)d_in[15], (const int*)d_in[17], (const int*)d_in[19], (const int*)d_in[21]};
    float* out = (float*)d_out;

    char* w = (char*)d_ws;
    auto alloc = [&](size_t bytes) {
        char* p = w;
        w += (bytes + 255) & ~(size_t)255;
        return p;
    };
    unsigned short* ha_bf = (unsigned short*)alloc((size_t)N_NODES * C * 2);
    unsigned short* hb_bf = (unsigned short*)alloc((size_t)N_NODES * C * 2);
    unsigned short* Qa    = (unsigned short*)alloc((size_t)N_NODES * C * 2);
    unsigned short* Qb    = (unsigned short*)alloc((size_t)N_NODES * C * 2);
    unsigned short* Kall  = (unsigned short*)alloc((size_t)4 * N_NODES * C * 2);
    unsigned short* Vall  = (unsigned short*)alloc((size_t)4 * N_NODES * C * 2);
    unsigned short* Wqt   = (unsigned short*)alloc(2 * C * C * 2);
    unsigned short* Wat   = (unsigned short*)alloc(2 * C * C * 2);
    unsigned short* Wkt   = (unsigned short*)alloc(4 * C * C * 2);
    unsigned short* Wvt   = (unsigned short*)alloc(4 * C * C * 2);
    float* bkt            = (float*)alloc(4 * C * 4);
    float* bvt            = (float*)alloc(4 * C * 4);
    int* cur              = (int*)alloc(4 * RANGES * 16 * 4);
    unsigned int* part    = (unsigned int*)alloc((size_t)4 * RANGES * CAP * 4);
    unsigned short* agg   = (unsigned short*)alloc((size_t)2 * N_NODES * C * 2);

    // prep
    zero_i32<<<(4 * RANGES * 16 + 255) / 256, 256, 0, stream>>>(cur, 4 * RANGES * 16);
    cvt_h<<<(N_NODES * C + 255) / 256, 256, 0, stream>>>(h_a, h_b, ha_bf, hb_bf);
    pack_wt<<<256, 128, 0, stream>>>(Wq, Wa, Wqt, Wat);
    fuse_w<<<32, 256, 0, stream>>>(Wk, Wv, bk, bv, att, msg, Wkt, Wvt, bkt, bvt);

    // P1: coarse partition (all 4 relations)
    part_k<<<dim3(1250, 4), 256, 0, stream>>>(srcs[0], srcs[1], srcs[2], srcs[3],
                                              dsts[0], dsts[1], dsts[2], dsts[3],
                                              cur, part);

    // all 10 projections in one dispatch
    proj_all<<<dim3(313, 10), 256, 0, stream>>>(ha_bf, hb_bf, Wqt, Wkt, Wvt, bq, bkt, bvt,
                                                Qa, Qb, Kall, Vall);

    // P2: both node types in one dispatch (type = blockIdx.x >= RANGES)
    node_p2<<<2 * RANGES, 256, 0, stream>>>(cur, part,
                                            (const unsigned int*)Kall, (const unsigned int*)Vall,
                                            pri,
                                            (const unsigned int*)Qa, (const unsigned int*)Qb,
                                            (unsigned int*)agg);

    // final skip-gated output, both types
    final_mm<<<dim3(313, 2), 256, 0, stream>>>(agg, Wat, ba, skip, h_a, h_b, out);
}

// Round 7
// 406.784 us; speedup vs baseline: 2.3496x; 1.0955x over previous
//
#include <hip/hip_runtime.h>
#include <stdint.h>

#define N_NODES 20000
#define N_EDGES 320000
#define C 128
#define H 8
#define D 16
#define SLOT 64       // max degree per node per relation (Poisson(16); P(>=64)~1e-18, guarded)
#define RANGESP 5000  // dst ranges of 4 nodes; 5000*4 == 20000 exactly
#define CAP 128       // per-(relation,range) record capacity; mean 64, P(>128)~1e-11/range, guarded

typedef short s16x8 __attribute__((ext_vector_type(8)));
typedef float f32x4 __attribute__((ext_vector_type(4)));

__device__ __forceinline__ unsigned short f2bf(float f) {
    unsigned int b = __float_as_uint(f);
    b += 0x7fffu + ((b >> 16) & 1u);
    return (unsigned short)(b >> 16);
}
__device__ __forceinline__ float bf2f(unsigned int u) {
    return __uint_as_float(u << 16);
}

// ---------------- utility ----------------
__global__ void zero_i32(int* p, int n) {
    int i = blockIdx.x * 256 + threadIdx.x;
    if (i < n) p[i] = 0;
}

__global__ void cvt_h(const float* ha, const float* hb, unsigned short* oa, unsigned short* ob) {
    int i = blockIdx.x * 256 + threadIdx.x;
    if (i < N_NODES * C) { oa[i] = f2bf(ha[i]); ob[i] = f2bf(hb[i]); }
}

// transpose-pack Wq and Wa to [type][out][in] bf16 for B-fragment loads
__global__ void pack_wt(const float* Wq, const float* Wa, unsigned short* Wqt, unsigned short* Wat) {
    int b = blockIdx.x;          // 2*128 blocks
    int t = b >> 7, n = b & 127;
    int i = threadIdx.x;         // 128 threads
    Wqt[(t * C + n) * C + i] = f2bf(Wq[(t * C + i) * C + n]);
    Wat[(t * C + n) * C + i] = f2bf(Wa[(t * C + i) * C + n]);
}

// fused relation weights: W~k[r] = Wk[type] @ blockdiag(att[r]), stored transposed bf16
__global__ void fuse_w(const float* Wk, const float* Wv, const float* bk, const float* bv,
                       const float* att, const float* msg,
                       unsigned short* Wkt, unsigned short* Wvt, float* bkt, float* bvt) {
    int r = blockIdx.x >> 3, h = blockIdx.x & 7;   // 32 blocks
    int t = r >> 1;                                 // src type: aa,ab from a; ba,bb from b
    __shared__ float sa[D * D], sm[D * D];
    int tid = threadIdx.x;
    if (tid < D * D) {
        sa[tid] = att[(r * H + h) * D * D + tid];
        sm[tid] = msg[(r * H + h) * D * D + tid];
    }
    __syncthreads();
    int i = tid & 127;
    for (int e = (tid >> 7); e < D; e += 2) {
        float sk = 0.f, sv = 0.f;
        for (int d = 0; d < D; ++d) {
            sk += Wk[(t * C + i) * C + h * D + d] * sa[d * D + e];
            sv += Wv[(t * C + i) * C + h * D + d] * sm[d * D + e];
        }
        Wkt[(r * C + h * D + e) * C + i] = f2bf(sk);
        Wvt[(r * C + h * D + e) * C + i] = f2bf(sv);
    }
    if (tid < D) {
        int e = tid;
        float sk = 0.f, sv = 0.f;
        for (int d = 0; d < D; ++d) {
            sk += bk[t * C + h * D + d] * sa[d * D + e];
            sv += bv[t * C + h * D + d] * sm[d * D + e];
        }
        bkt[r * C + h * D + e] = sk;
        bvt[r * C + h * D + e] = sv;
    }
}

// ---------------- fused MFMA projections: 10 jobs via blockIdx.y ----------------
__global__ __launch_bounds__(256) void proj_all(const unsigned short* __restrict__ ha,
                                                const unsigned short* __restrict__ hb,
                                                const unsigned short* __restrict__ Wqt,
                                                const unsigned short* __restrict__ Wkt,
                                                const unsigned short* __restrict__ Wvt,
                                                const float* __restrict__ bq,
                                                const float* __restrict__ bkt,
                                                const float* __restrict__ bvt,
                                                unsigned short* __restrict__ Qa,
                                                unsigned short* __restrict__ Qb,
                                                unsigned short* __restrict__ Kall,
                                                unsigned short* __restrict__ Vall) {
    int j = blockIdx.y;
    const unsigned short* A;
    const unsigned short* Wt;
    const float* bias;
    unsigned short* Out;
    if (j < 2) {
        A = j ? hb : ha; Wt = Wqt + j * C * C; bias = bq + j * C; Out = j ? Qb : Qa;
    } else if (j < 6) {
        int r = j - 2;
        A = (r < 2) ? ha : hb; Wt = Wkt + r * C * C; bias = bkt + r * C;
        Out = Kall + (size_t)r * N_NODES * C;
    } else {
        int r = j - 6;
        A = (r < 2) ? ha : hb; Wt = Wvt + r * C * C; bias = bvt + r * C;
        Out = Vall + (size_t)r * N_NODES * C;
    }
    int wid = threadIdx.x >> 6, l = threadIdx.x & 63;
    int row_base = blockIdx.x * 64 + wid * 16;
    int lm = l & 15, q = l >> 4;
    f32x4 acc[8] = {};
    int arow = row_base + lm;
    if (arow >= N_NODES) arow = N_NODES - 1;
    const s16x8* Ap = (const s16x8*)(A + (size_t)arow * C);
#pragma unroll
    for (int kc = 0; kc < 4; ++kc) {
        s16x8 af = Ap[kc * 4 + q];
#pragma unroll
        for (int t = 0; t < 8; ++t) {
            s16x8 bf = *(const s16x8*)(Wt + (t * 16 + lm) * C + kc * 32 + q * 8);
            acc[t] = __builtin_amdgcn_mfma_f32_16x16x32_bf16(af, bf, acc[t], 0, 0, 0);
        }
    }
#pragma unroll
    for (int t = 0; t < 8; ++t) {
        int col = t * 16 + lm;
        float b = bias[col];
#pragma unroll
        for (int i = 0; i < 4; ++i) {
            int row = row_base + q * 4 + i;
            if (row < N_NODES) Out[(size_t)row * C + col] = f2bf(acc[t][i] + b);
        }
    }
}

// ---------------- final: out = al*(agg @ Wa + ba) + (1-al)*h ; both types via blockIdx.y ----------------
__global__ __launch_bounds__(256) void final_mm(const unsigned short* __restrict__ AggAll,
                                                const unsigned short* __restrict__ WatAll,
                                                const float* __restrict__ baAll,
                                                const float* __restrict__ skip,
                                                const float* __restrict__ h_a,
                                                const float* __restrict__ h_b,
                                                float* __restrict__ OutAll) {
    int ty = blockIdx.y;
    const unsigned short* Agg = AggAll + (size_t)ty * N_NODES * C;
    const unsigned short* Wat = WatAll + ty * C * C;
    const float* ba = baAll + ty * C;
    const float* h_orig = ty ? h_b : h_a;
    float* Out = OutAll + (size_t)ty * N_NODES * C;
    int wid = threadIdx.x >> 6, l = threadIdx.x & 63;
    int row_base = blockIdx.x * 64 + wid * 16;
    int lm = l & 15, q = l >> 4;
    f32x4 acc[8] = {};
    int arow = row_base + lm;
    if (arow >= N_NODES) arow = N_NODES - 1;
    const s16x8* Ap = (const s16x8*)(Agg + (size_t)arow * C);
#pragma unroll
    for (int kc = 0; kc < 4; ++kc) {
        s16x8 af = Ap[kc * 4 + q];
#pragma unroll
        for (int t = 0; t < 8; ++t) {
            s16x8 bf = *(const s16x8*)(Wat + (t * 16 + lm) * C + kc * 32 + q * 8);
            acc[t] = __builtin_amdgcn_mfma_f32_16x16x32_bf16(af, bf, acc[t], 0, 0, 0);
        }
    }
    float al = 1.f / (1.f + __expf(-skip[ty]));
#pragma unroll
    for (int t = 0; t < 8; ++t) {
        int col = t * 16 + lm;
        float b = ba[col];
#pragma unroll
        for (int i = 0; i < 4; ++i) {
            int row = row_base + q * 4 + i;
            if (row < N_NODES)
                Out[(size_t)row * C + col] = al * (acc[t][i] + b) + (1.f - al) * h_orig[(size_t)row * C + col];
        }
    }
}

// ---------------- P1: coarse partition into 5000 dst-ranges (of 4 nodes) per relation ----------------
// Writes per range are cursor-sequential -> frontier stays L2-resident (no
// partial-line HBM write amplification). 64 edges/cursor mean -> low same-address
// atomic contention.
__global__ void part_k(const int* s0, const int* s1, const int* s2, const int* s3,
                       const int* d0, const int* d1, const int* d2, const int* d3,
                       int* cur, unsigned int* part) {
    int e = blockIdx.x * 256 + threadIdx.x;
    int r = blockIdx.y;
    const int* dd = (r == 0) ? d0 : (r == 1) ? d1 : (r == 2) ? d2 : d3;
    const int* ss = (r == 0) ? s0 : (r == 1) ? s1 : (r == 2) ? s2 : s3;
    if (e < N_EDGES) {
        int d = dd[e];
        int range = d >> 2;
        int pos = atomicAdd(&cur[(r * RANGESP + range) * 16], 1);   // stride 16: one cursor per 64B line
        if (pos < CAP)
            part[((size_t)(r * RANGESP + range)) * CAP + pos] =
                (unsigned int)ss[e] | ((unsigned int)(d & 3) << 16);
    }
}

// ---------------- P2: LDS-bin + fused scoring/softmax/aggregate ----------------
// One block per (type, range-of-4-dsts): 10000 blocks = 40000 waves, ONE dst
// per wave (max TLP for the latency-bound gather loop). Binning is a ~64-record
// coalesced read + tiny LDS scatter.
__global__ __launch_bounds__(256) void node_p2(const int* __restrict__ cur,
                                               const unsigned int* __restrict__ part,
                                               const unsigned int* __restrict__ Kall,
                                               const unsigned int* __restrict__ Vall,
                                               const float* __restrict__ pri,
                                               const unsigned int* __restrict__ Qa,
                                               const unsigned int* __restrict__ Qb,
                                               unsigned int* __restrict__ agg) {
    __shared__ unsigned short slot[2][4][SLOT];
    __shared__ int cnt[2][4];
    int g = blockIdx.x;
    int type = (g >= RANGESP) ? 1 : 0;
    int range = g - type * RANGESP;
    int relA = type ? 1 : 0;           // ab : aa
    int relB = type ? 3 : 2;           // bb : ba
    if (threadIdx.x < 8) ((int*)cnt)[threadIdx.x] = 0;
    __syncthreads();
#pragma unroll
    for (int rr = 0; rr < 2; ++rr) {
        int rel = rr ? relB : relA;
        int c = cur[(rel * RANGESP + range) * 16];
        if (c > CAP) c = CAP;
        const unsigned int* pp = part + ((size_t)(rel * RANGESP + range)) * CAP;
        for (int i = threadIdx.x; i < c; i += 256) {
            unsigned int rec = pp[i];
            int dof = rec >> 16;
            int p = atomicAdd(&cnt[rr][dof], 1);
            if (p < SLOT) slot[rr][dof][p] = (unsigned short)(rec & 0xffffu);
        }
    }
    __syncthreads();

    int wid = threadIdx.x >> 6, l = threadIdx.x & 63;
    int hg = l >> 3;
    int dof = wid;                      // ONE dst per wave
    int n = range * 4 + dof;
    const unsigned int* Q32 = type ? Qb : Qa;
    unsigned int qv = Q32[(size_t)n * 64 + l];
    float q0 = bf2f(qv & 0xffffu), q1 = bf2f(qv >> 16);
    float outx = 0.f, outy = 0.f;

#pragma unroll 1
    for (int rr = 0; rr < 2; ++rr) {
        int rel = rr ? relB : relA;
        const unsigned int* K32 = Kall + (size_t)rel * N_NODES * 64;
        const unsigned int* V32 = Vall + (size_t)rel * N_NODES * 64;
        float pv = pri[rel * 8 + hg] * 0.25f;
        int deg = cnt[rr][dof];
        if (deg > SLOT) deg = SLOT;
        float m = -1e30f, sum = 0.f;
        float ax0 = 0.f, ay0 = 0.f, ax1 = 0.f, ay1 = 0.f;
        for (int base = 0; base < deg; base += 16) {
            int cc = deg - base;
            if (cc > 16) cc = 16;
            float s[16];
            unsigned int vv[16];
#pragma unroll
            for (int i = 0; i < 16; ++i) {
                float d = -1e30f;
                unsigned int v = 0;
                if (i < cc) {
                    int sv = slot[rr][dof][base + i];   // LDS broadcast (conflict-free)
                    unsigned int kv = K32[(size_t)sv * 64 + l];
                    v = V32[(size_t)sv * 64 + l];       // fetched with K (indep of max)
                    d = q0 * bf2f(kv & 0xffffu) + q1 * bf2f(kv >> 16);
                    d += __shfl_xor(d, 1);
                    d += __shfl_xor(d, 2);
                    d += __shfl_xor(d, 4);              // full dot in all 8 lanes of head
                    d *= pv;
                }
                s[i] = d;
                vv[i] = v;
            }
            float mloc = s[0];
#pragma unroll
            for (int i = 1; i < 16; ++i) mloc = fmaxf(mloc, s[i]);
            float mnew = fmaxf(m, mloc);
            float alpha = __expf(m - mnew);             // first chunk: exp(-inf)=0
            sum *= alpha; ax0 *= alpha; ay0 *= alpha; ax1 *= alpha; ay1 *= alpha;
            m = mnew;
#pragma unroll
            for (int i = 0; i < 16; i += 2) {
                if (i < cc) {
                    float ww = __expf(s[i] - m);
                    sum += ww;
                    ax0 += ww * bf2f(vv[i] & 0xffffu);
                    ay0 += ww * bf2f(vv[i] >> 16);
                }
                if (i + 1 < cc) {
                    float ww = __expf(s[i + 1] - m);
                    sum += ww;
                    ax1 += ww * bf2f(vv[i + 1] & 0xffffu);
                    ay1 += ww * bf2f(vv[i + 1] >> 16);
                }
            }
        }
        if (deg > 0) {
            float rs = 1.f / sum;
            outx += (ax0 + ax1) * rs;
            outy += (ay0 + ay1) * rs;
        }
    }
    // 0.5 = cross_reducer 'mean'; agg stored bf16-packed
    unsigned int packed = (unsigned int)f2bf(0.5f * outx) | ((unsigned int)f2bf(0.5f * outy) << 16);
    agg[((size_t)type * N_NODES + n) * 64 + l] = packed;
}

extern "C" void kernel_launch(void* const* d_in, const int* in_sizes, int n_in,
                              void* d_out, int out_size, void* d_ws, size_t ws_size,
                              hipStream_t stream) {
    const float* h_a  = (const float*)d_in[0];
    const float* h_b  = (const float*)d_in[1];
    const float* Wk   = (const float*)d_in[2];
    const float* bk   = (const float*)d_in[3];
    const float* Wq   = (const float*)d_in[4];
    const float* bq   = (const float*)d_in[5];
    const float* Wv   = (const float*)d_in[6];
    const float* bv   = (const float*)d_in[7];
    const float* Wa   = (const float*)d_in[8];
    const float* ba   = (const float*)d_in[9];
    const float* att  = (const float*)d_in[10];
    const float* msg  = (const float*)d_in[11];
    const float* pri  = (const float*)d_in[12];
    const float* skip = (const float*)d_in[13];
    const int* srcs[4] = {(const int*)d_in[14], (const int*)d_in[16], (const int*)d_in[18], (const int*)d_in[20]};
    const int* dsts[4] = {(const int*)d_in[15], (const int*)d_in[17], (const int*)d_in[19], (const int*)d_in[21]};
    float* out = (float*)d_out;

    char* w = (char*)d_ws;
    auto alloc = [&](size_t bytes) {
        char* p = w;
        w += (bytes + 255) & ~(size_t)255;
        return p;
    };
    unsigned short* ha_bf = (unsigned short*)alloc((size_t)N_NODES * C * 2);
    unsigned short* hb_bf = (unsigned short*)alloc((size_t)N_NODES * C * 2);
    unsigned short* Qa    = (unsigned short*)alloc((size_t)N_NODES * C * 2);
    unsigned short* Qb    = (unsigned short*)alloc((size_t)N_NODES * C * 2);
    unsigned short* Kall  = (unsigned short*)alloc((size_t)4 * N_NODES * C * 2);
    unsigned short* Vall  = (unsigned short*)alloc((size_t)4 * N_NODES * C * 2);
    unsigned short* Wqt   = (unsigned short*)alloc(2 * C * C * 2);
    unsigned short* Wat   = (unsigned short*)alloc(2 * C * C * 2);
    unsigned short* Wkt   = (unsigned short*)alloc(4 * C * C * 2);
    unsigned short* Wvt   = (unsigned short*)alloc(4 * C * C * 2);
    float* bkt            = (float*)alloc(4 * C * 4);
    float* bvt            = (float*)alloc(4 * C * 4);
    int* cur              = (int*)alloc(4 * RANGESP * 16 * 4);
    unsigned int* part    = (unsigned int*)alloc((size_t)4 * RANGESP * CAP * 4);
    unsigned short* agg   = (unsigned short*)alloc((size_t)2 * N_NODES * C * 2);

    // prep
    zero_i32<<<(4 * RANGESP * 16 + 255) / 256, 256, 0, stream>>>(cur, 4 * RANGESP * 16);
    cvt_h<<<(N_NODES * C + 255) / 256, 256, 0, stream>>>(h_a, h_b, ha_bf, hb_bf);
    pack_wt<<<256, 128, 0, stream>>>(Wq, Wa, Wqt, Wat);
    fuse_w<<<32, 256, 0, stream>>>(Wk, Wv, bk, bv, att, msg, Wkt, Wvt, bkt, bvt);

    // P1: coarse partition (all 4 relations)
    part_k<<<dim3(1250, 4), 256, 0, stream>>>(srcs[0], srcs[1], srcs[2], srcs[3],
                                              dsts[0], dsts[1], dsts[2], dsts[3],
                                              cur, part);

    // all 10 projections in one dispatch
    proj_all<<<dim3(313, 10), 256, 0, stream>>>(ha_bf, hb_bf, Wqt, Wkt, Wvt, bq, bkt, bvt,
                                                Qa, Qb, Kall, Vall);

    // P2: both node types in one dispatch; 1 dst per wave
    node_p2<<<2 * RANGESP, 256, 0, stream>>>(cur, part,
                                             (const unsigned int*)Kall, (const unsigned int*)Vall,
                                             pri,
                                             (const unsigned int*)Qa, (const unsigned int*)Qb,
                                             (unsigned int*)agg);

    // final skip-gated output, both types
    final_mm<<<dim3(313, 2), 256, 0, stream>>>(agg, Wat, ba, skip, h_a, h_b, out);
}

// Round 8
// 396.498 us; speedup vs baseline: 2.4105x; 1.0259x over previous
//
#include <hip/hip_runtime.h>
#include <stdint.h>

#define N_NODES 20000
#define N_EDGES 320000
#define C 128
#define H 8
#define D 16
#define SLOT 64       // max degree per node per relation (Poisson(16); P(>=64)~1e-18, guarded)
#define RANGESP 5000  // dst ranges of 4 nodes; 5000*4 == 20000 exactly
#define CAP 128       // per-(relation,range) record capacity; mean 64, guarded

// prep_k job partition (block ranges)
#define P_CVT 2500    // 2500*256*4 == 2,560,000 == N_NODES*C exactly
#define P_ZERO 313    // 80000 int4 == 320000 ints == 4*RANGESP*16
#define P_PACK 128
#define P_FUSE 32
// mega_k job partition
#define MB_PART 5000  // 4 relations x 1250 blocks; 1250*256 == N_EDGES exactly
#define MB_PROJ 3130  // 10 jobs x 313 blocks

typedef short s16x8 __attribute__((ext_vector_type(8)));
typedef float f32x4 __attribute__((ext_vector_type(4)));

__device__ __forceinline__ unsigned short f2bf(float f) {
    unsigned int b = __float_as_uint(f);
    b += 0x7fffu + ((b >> 16) & 1u);
    return (unsigned short)(b >> 16);
}
__device__ __forceinline__ float bf2f(unsigned int u) {
    return __uint_as_float(u << 16);
}

// ---------------- prep: cvt_h + zero-cursors + pack_wt + fuse_w in ONE dispatch ----------------
__global__ __launch_bounds__(256) void prep_k(const float* __restrict__ h_a, const float* __restrict__ h_b,
                                              unsigned short* __restrict__ oa, unsigned short* __restrict__ ob,
                                              const float* __restrict__ Wq, const float* __restrict__ Wa,
                                              unsigned short* __restrict__ Wqt, unsigned short* __restrict__ Wat,
                                              const float* __restrict__ Wk, const float* __restrict__ Wv,
                                              const float* __restrict__ bk, const float* __restrict__ bv,
                                              const float* __restrict__ att, const float* __restrict__ msg,
                                              unsigned short* __restrict__ Wkt, unsigned short* __restrict__ Wvt,
                                              float* __restrict__ bkt, float* __restrict__ bvt,
                                              int* __restrict__ cur) {
    __shared__ float sa[D * D], sm[D * D];
    int bid = blockIdx.x;
    int tid = threadIdx.x;
    if (bid < P_CVT) {
        // bf16 conversion of h_a/h_b, float4 -> ushort4
        int i = (bid * 256 + tid) * 4;
        float4 va = *(const float4*)(h_a + i);
        float4 vb = *(const float4*)(h_b + i);
        ushort4 ua = { f2bf(va.x), f2bf(va.y), f2bf(va.z), f2bf(va.w) };
        ushort4 ub = { f2bf(vb.x), f2bf(vb.y), f2bf(vb.z), f2bf(vb.w) };
        *(ushort4*)(oa + i) = ua;
        *(ushort4*)(ob + i) = ub;
        return;
    }
    bid -= P_CVT;
    if (bid < P_ZERO) {
        int i = bid * 256 + tid;
        if (i < 80000) ((int4*)cur)[i] = make_int4(0, 0, 0, 0);
        return;
    }
    bid -= P_ZERO;
    if (bid < P_PACK) {
        // transpose-pack Wq and Wa to [type][out][in] bf16
        int n = bid;
        int t = tid >> 7, i = tid & 127;
        Wqt[(t * C + n) * C + i] = f2bf(Wq[(t * C + i) * C + n]);
        Wat[(t * C + n) * C + i] = f2bf(Wa[(t * C + i) * C + n]);
        return;
    }
    bid -= P_PACK;
    // fuse_w: W~k[r] = Wk[type] @ blockdiag(att[r]) etc., 32 blocks
    {
        int r = bid >> 3, h = bid & 7;
        int t = r >> 1;
        if (tid < D * D) {
            sa[tid] = att[(r * H + h) * D * D + tid];
            sm[tid] = msg[(r * H + h) * D * D + tid];
        }
        __syncthreads();
        int i = tid & 127;
        for (int e = (tid >> 7); e < D; e += 2) {
            float sk = 0.f, sv = 0.f;
            for (int d = 0; d < D; ++d) {
                sk += Wk[(t * C + i) * C + h * D + d] * sa[d * D + e];
                sv += Wv[(t * C + i) * C + h * D + d] * sm[d * D + e];
            }
            Wkt[(r * C + h * D + e) * C + i] = f2bf(sk);
            Wvt[(r * C + h * D + e) * C + i] = f2bf(sv);
        }
        if (tid < D) {
            int e = tid;
            float sk = 0.f, sv = 0.f;
            for (int d = 0; d < D; ++d) {
                sk += bk[t * C + h * D + d] * sa[d * D + e];
                sv += bv[t * C + h * D + d] * sm[d * D + e];
            }
            bkt[r * C + h * D + e] = sk;
            bvt[r * C + h * D + e] = sv;
        }
    }
}

// ---------------- mega: edge partition (latency-bound) || projections (MFMA-bound) ----------------
// Horizontally fused: independent work, complementary pipes -> co-scheduled on CUs,
// cost ~= max of the two instead of sum.
__global__ __launch_bounds__(256) void mega_k(const int* __restrict__ s0, const int* __restrict__ s1,
                                              const int* __restrict__ s2, const int* __restrict__ s3,
                                              const int* __restrict__ d0, const int* __restrict__ d1,
                                              const int* __restrict__ d2, const int* __restrict__ d3,
                                              int* __restrict__ cur, unsigned int* __restrict__ part,
                                              const unsigned short* __restrict__ ha,
                                              const unsigned short* __restrict__ hb,
                                              const unsigned short* __restrict__ Wqt,
                                              const unsigned short* __restrict__ Wkt,
                                              const unsigned short* __restrict__ Wvt,
                                              const float* __restrict__ bq,
                                              const float* __restrict__ bkt,
                                              const float* __restrict__ bvt,
                                              unsigned short* __restrict__ Qa,
                                              unsigned short* __restrict__ Qb,
                                              unsigned short* __restrict__ Kall,
                                              unsigned short* __restrict__ Vall) {
    int bid = blockIdx.x;
    if (bid < MB_PART) {
        // ---- partition path: cursor-sequential scatter, L2-resident frontier ----
        int r = bid / 1250;
        int eb = bid - r * 1250;
        int e = eb * 256 + threadIdx.x;          // 1250*256 == N_EDGES, no guard needed
        const int* dd = (r == 0) ? d0 : (r == 1) ? d1 : (r == 2) ? d2 : d3;
        const int* ss = (r == 0) ? s0 : (r == 1) ? s1 : (r == 2) ? s2 : s3;
        int d = dd[e];
        int range = d >> 2;
        int pos = atomicAdd(&cur[(r * RANGESP + range) * 16], 1);  // one cursor per 64B line
        if (pos < CAP)
            part[((size_t)(r * RANGESP + range)) * CAP + pos] =
                (unsigned int)ss[e] | ((unsigned int)(d & 3) << 16);
        return;
    }
    // ---- projection path: 10 jobs x 313 blocks ----
    int pb = bid - MB_PART;
    int j = pb / 313;
    int xb = pb - j * 313;
    const unsigned short* A;
    const unsigned short* Wt;
    const float* bias;
    unsigned short* Out;
    if (j < 2) {
        A = j ? hb : ha; Wt = Wqt + j * C * C; bias = bq + j * C; Out = j ? Qb : Qa;
    } else if (j < 6) {
        int r = j - 2;
        A = (r < 2) ? ha : hb; Wt = Wkt + r * C * C; bias = bkt + r * C;
        Out = Kall + (size_t)r * N_NODES * C;
    } else {
        int r = j - 6;
        A = (r < 2) ? ha : hb; Wt = Wvt + r * C * C; bias = bvt + r * C;
        Out = Vall + (size_t)r * N_NODES * C;
    }
    int wid = threadIdx.x >> 6, l = threadIdx.x & 63;
    int row_base = xb * 64 + wid * 16;
    int lm = l & 15, q = l >> 4;
    f32x4 acc[8] = {};
    int arow = row_base + lm;
    if (arow >= N_NODES) arow = N_NODES - 1;
    const s16x8* Ap = (const s16x8*)(A + (size_t)arow * C);
#pragma unroll
    for (int kc = 0; kc < 4; ++kc) {
        s16x8 af = Ap[kc * 4 + q];
#pragma unroll
        for (int t = 0; t < 8; ++t) {
            s16x8 bf = *(const s16x8*)(Wt + (t * 16 + lm) * C + kc * 32 + q * 8);
            acc[t] = __builtin_amdgcn_mfma_f32_16x16x32_bf16(af, bf, acc[t], 0, 0, 0);
        }
    }
#pragma unroll
    for (int t = 0; t < 8; ++t) {
        int col = t * 16 + lm;
        float b = bias[col];
#pragma unroll
        for (int i = 0; i < 4; ++i) {
            int row = row_base + q * 4 + i;
            if (row < N_NODES) Out[(size_t)row * C + col] = f2bf(acc[t][i] + b);
        }
    }
}

// ---------------- final: out = al*(agg @ Wa + ba) + (1-al)*h ; both types via blockIdx.y ----------------
__global__ __launch_bounds__(256) void final_mm(const unsigned short* __restrict__ AggAll,
                                                const unsigned short* __restrict__ WatAll,
                                                const float* __restrict__ baAll,
                                                const float* __restrict__ skip,
                                                const float* __restrict__ h_a,
                                                const float* __restrict__ h_b,
                                                float* __restrict__ OutAll) {
    int ty = blockIdx.y;
    const unsigned short* Agg = AggAll + (size_t)ty * N_NODES * C;
    const unsigned short* Wat = WatAll + ty * C * C;
    const float* ba = baAll + ty * C;
    const float* h_orig = ty ? h_b : h_a;
    float* Out = OutAll + (size_t)ty * N_NODES * C;
    int wid = threadIdx.x >> 6, l = threadIdx.x & 63;
    int row_base = blockIdx.x * 64 + wid * 16;
    int lm = l & 15, q = l >> 4;
    f32x4 acc[8] = {};
    int arow = row_base + lm;
    if (arow >= N_NODES) arow = N_NODES - 1;
    const s16x8* Ap = (const s16x8*)(Agg + (size_t)arow * C);
#pragma unroll
    for (int kc = 0; kc < 4; ++kc) {
        s16x8 af = Ap[kc * 4 + q];
#pragma unroll
        for (int t = 0; t < 8; ++t) {
            s16x8 bf = *(const s16x8*)(Wat + (t * 16 + lm) * C + kc * 32 + q * 8);
            acc[t] = __builtin_amdgcn_mfma_f32_16x16x32_bf16(af, bf, acc[t], 0, 0, 0);
        }
    }
    float al = 1.f / (1.f + __expf(-skip[ty]));
#pragma unroll
    for (int t = 0; t < 8; ++t) {
        int col = t * 16 + lm;
        float b = ba[col];
#pragma unroll
        for (int i = 0; i < 4; ++i) {
            int row = row_base + q * 4 + i;
            if (row < N_NODES)
                Out[(size_t)row * C + col] = al * (acc[t][i] + b) + (1.f - al) * h_orig[(size_t)row * C + col];
        }
    }
}

// ---------------- P2: LDS-bin + fused scoring/softmax/aggregate ----------------
// One block per (type, range-of-4-dsts): 10000 blocks = 40000 waves, ONE dst per wave.
__global__ __launch_bounds__(256) void node_p2(const int* __restrict__ cur,
                                               const unsigned int* __restrict__ part,
                                               const unsigned int* __restrict__ Kall,
                                               const unsigned int* __restrict__ Vall,
                                               const float* __restrict__ pri,
                                               const unsigned int* __restrict__ Qa,
                                               const unsigned int* __restrict__ Qb,
                                               unsigned int* __restrict__ agg) {
    __shared__ unsigned short slot[2][4][SLOT];
    __shared__ int cnt[2][4];
    int g = blockIdx.x;
    int type = (g >= RANGESP) ? 1 : 0;
    int range = g - type * RANGESP;
    int relA = type ? 1 : 0;           // ab : aa
    int relB = type ? 3 : 2;           // bb : ba
    if (threadIdx.x < 8) ((int*)cnt)[threadIdx.x] = 0;
    __syncthreads();
#pragma unroll
    for (int rr = 0; rr < 2; ++rr) {
        int rel = rr ? relB : relA;
        int c = cur[(rel * RANGESP + range) * 16];
        if (c > CAP) c = CAP;
        const unsigned int* pp = part + ((size_t)(rel * RANGESP + range)) * CAP;
        for (int i = threadIdx.x; i < c; i += 256) {
            unsigned int rec = pp[i];
            int dof = rec >> 16;
            int p = atomicAdd(&cnt[rr][dof], 1);
            if (p < SLOT) slot[rr][dof][p] = (unsigned short)(rec & 0xffffu);
        }
    }
    __syncthreads();

    int wid = threadIdx.x >> 6, l = threadIdx.x & 63;
    int hg = l >> 3;
    int dof = wid;                      // ONE dst per wave
    int n = range * 4 + dof;
    const unsigned int* Q32 = type ? Qb : Qa;
    unsigned int qv = Q32[(size_t)n * 64 + l];
    float q0 = bf2f(qv & 0xffffu), q1 = bf2f(qv >> 16);
    float outx = 0.f, outy = 0.f;

#pragma unroll 1
    for (int rr = 0; rr < 2; ++rr) {
        int rel = rr ? relB : relA;
        const unsigned int* K32 = Kall + (size_t)rel * N_NODES * 64;
        const unsigned int* V32 = Vall + (size_t)rel * N_NODES * 64;
        float pv = pri[rel * 8 + hg] * 0.25f;
        int deg = cnt[rr][dof];
        if (deg > SLOT) deg = SLOT;
        float m = -1e30f, sum = 0.f;
        float ax0 = 0.f, ay0 = 0.f, ax1 = 0.f, ay1 = 0.f;
        for (int base = 0; base < deg; base += 16) {
            int cc = deg - base;
            if (cc > 16) cc = 16;
            float s[16];
            unsigned int vv[16];
#pragma unroll
            for (int i = 0; i < 16; ++i) {
                float d = -1e30f;
                unsigned int v = 0;
                if (i < cc) {
                    int sv = slot[rr][dof][base + i];   // LDS broadcast (conflict-free)
                    unsigned int kv = K32[(size_t)sv * 64 + l];
                    v = V32[(size_t)sv * 64 + l];       // fetched with K (indep of max)
                    d = q0 * bf2f(kv & 0xffffu) + q1 * bf2f(kv >> 16);
                    d += __shfl_xor(d, 1);
                    d += __shfl_xor(d, 2);
                    d += __shfl_xor(d, 4);              // full dot in all 8 lanes of head
                    d *= pv;
                }
                s[i] = d;
                vv[i] = v;
            }
            float mloc = s[0];
#pragma unroll
            for (int i = 1; i < 16; ++i) mloc = fmaxf(mloc, s[i]);
            float mnew = fmaxf(m, mloc);
            float alpha = __expf(m - mnew);             // first chunk: exp(-inf)=0
            sum *= alpha; ax0 *= alpha; ay0 *= alpha; ax1 *= alpha; ay1 *= alpha;
            m = mnew;
#pragma unroll
            for (int i = 0; i < 16; i += 2) {
                if (i < cc) {
                    float ww = __expf(s[i] - m);
                    sum += ww;
                    ax0 += ww * bf2f(vv[i] & 0xffffu);
                    ay0 += ww * bf2f(vv[i] >> 16);
                }
                if (i + 1 < cc) {
                    float ww = __expf(s[i + 1] - m);
                    sum += ww;
                    ax1 += ww * bf2f(vv[i + 1] & 0xffffu);
                    ay1 += ww * bf2f(vv[i + 1] >> 16);
                }
            }
        }
        if (deg > 0) {
            float rs = 1.f / sum;
            outx += (ax0 + ax1) * rs;
            outy += (ay0 + ay1) * rs;
        }
    }
    // 0.5 = cross_reducer 'mean'; agg stored bf16-packed
    unsigned int packed = (unsigned int)f2bf(0.5f * outx) | ((unsigned int)f2bf(0.5f * outy) << 16);
    agg[((size_t)type * N_NODES + n) * 64 + l] = packed;
}

extern "C" void kernel_launch(void* const* d_in, const int* in_sizes, int n_in,
                              void* d_out, int out_size, void* d_ws, size_t ws_size,
                              hipStream_t stream) {
    const float* h_a  = (const float*)d_in[0];
    const float* h_b  = (const float*)d_in[1];
    const float* Wk   = (const float*)d_in[2];
    const float* bk   = (const float*)d_in[3];
    const float* Wq   = (const float*)d_in[4];
    const float* bq   = (const float*)d_in[5];
    const float* Wv   = (const float*)d_in[6];
    const float* bv   = (const float*)d_in[7];
    const float* Wa   = (const float*)d_in[8];
    const float* ba   = (const float*)d_in[9];
    const float* att  = (const float*)d_in[10];
    const float* msg  = (const float*)d_in[11];
    const float* pri  = (const float*)d_in[12];
    const float* skip = (const float*)d_in[13];
    const int* srcs[4] = {(const int*)d_in[14], (const int*)d_in[16], (const int*)d_in[18], (const int*)d_in[20]};
    const int* dsts[4] = {(const int*)d_in[15], (const int*)d_in[17], (const int*)d_in[19], (const int*)d_in[21]};
    float* out = (float*)d_out;

    char* w = (char*)d_ws;
    auto alloc = [&](size_t bytes) {
        char* p = w;
        w += (bytes + 255) & ~(size_t)255;
        return p;
    };
    unsigned short* ha_bf = (unsigned short*)alloc((size_t)N_NODES * C * 2);
    unsigned short* hb_bf = (unsigned short*)alloc((size_t)N_NODES * C * 2);
    unsigned short* Qa    = (unsigned short*)alloc((size_t)N_NODES * C * 2);
    unsigned short* Qb    = (unsigned short*)alloc((size_t)N_NODES * C * 2);
    unsigned short* Kall  = (unsigned short*)alloc((size_t)4 * N_NODES * C * 2);
    unsigned short* Vall  = (unsigned short*)alloc((size_t)4 * N_NODES * C * 2);
    unsigned short* Wqt   = (unsigned short*)alloc(2 * C * C * 2);
    unsigned short* Wat   = (unsigned short*)alloc(2 * C * C * 2);
    unsigned short* Wkt   = (unsigned short*)alloc(4 * C * C * 2);
    unsigned short* Wvt   = (unsigned short*)alloc(4 * C * C * 2);
    float* bkt            = (float*)alloc(4 * C * 4);
    float* bvt            = (float*)alloc(4 * C * 4);
    int* cur              = (int*)alloc(4 * RANGESP * 16 * 4);
    unsigned int* part    = (unsigned int*)alloc((size_t)4 * RANGESP * CAP * 4);
    unsigned short* agg   = (unsigned short*)alloc((size_t)2 * N_NODES * C * 2);

    // 1) fused prep: cvt + zero-cursors + pack + fuse
    prep_k<<<P_CVT + P_ZERO + P_PACK + P_FUSE, 256, 0, stream>>>(
        h_a, h_b, ha_bf, hb_bf, Wq, Wa, Wqt, Wat,
        Wk, Wv, bk, bv, att, msg, Wkt, Wvt, bkt, bvt, cur);

    // 2) fused partition || projections
    mega_k<<<MB_PART + MB_PROJ, 256, 0, stream>>>(
        srcs[0], srcs[1], srcs[2], srcs[3],
        dsts[0], dsts[1], dsts[2], dsts[3],
        cur, part,
        ha_bf, hb_bf, Wqt, Wkt, Wvt, bq, bkt, bvt,
        Qa, Qb, Kall, Vall);

    // 3) fused scoring + softmax + aggregate; 1 dst per wave
    node_p2<<<2 * RANGESP, 256, 0, stream>>>(cur, part,
                                             (const unsigned int*)Kall, (const unsigned int*)Vall,
                                             pri,
                                             (const unsigned int*)Qa, (const unsigned int*)Qb,
                                             (unsigned int*)agg);

    // 4) final skip-gated output, both types
    final_mm<<<dim3(313, 2), 256, 0, stream>>>(agg, Wat, ba, skip, h_a, h_b, out);
}

// Round 9
// 349.146 us; speedup vs baseline: 2.7375x; 1.1356x over previous
//
#include <hip/hip_runtime.h>
#include <stdint.h>

#define N_NODES 20000
#define N_EDGES 320000
#define C 128
#define H 8
#define D 16
#define SLOT 64        // max degree per node per relation (Poisson(16); P(>=64)~1e-18, guarded)
#define NRANGE 5000    // node_p2 ranges of 4 dsts
#define RANGES2 10000  // partition ranges of 2 dsts; 10000*2 == 20000
#define CAP2 80        // records per (rel,range2); mean 32, P(>=80)~1e-11, guarded

// prep_k job partition (block ranges)
#define P_CVT 2500     // 2500*256*4 == N_NODES*C
#define P_ZERO 625     // 40000 cursors * 16 ints = 640000 ints = 160000 int4
#define P_PACK 128
#define P_FUSE 32
// mega_k: 5000 part blocks + 3130 proj blocks, period-13 interleave (8 part + 5 proj)
#define MB_TOTAL 8130

typedef short s16x8 __attribute__((ext_vector_type(8)));
typedef float f32x4 __attribute__((ext_vector_type(4)));

__device__ __forceinline__ unsigned short f2bf(float f) {
    unsigned int b = __float_as_uint(f);
    b += 0x7fffu + ((b >> 16) & 1u);
    return (unsigned short)(b >> 16);
}
__device__ __forceinline__ float bf2f(unsigned int u) {
    return __uint_as_float(u << 16);
}

// ---------------- prep: cvt_h + zero-cursors + pack_wt + fuse_w in ONE dispatch ----------------
__global__ __launch_bounds__(256) void prep_k(const float* __restrict__ h_a, const float* __restrict__ h_b,
                                              unsigned short* __restrict__ oa, unsigned short* __restrict__ ob,
                                              const float* __restrict__ Wq, const float* __restrict__ Wa,
                                              unsigned short* __restrict__ Wqt, unsigned short* __restrict__ Wat,
                                              const float* __restrict__ Wk, const float* __restrict__ Wv,
                                              const float* __restrict__ bk, const float* __restrict__ bv,
                                              const float* __restrict__ att, const float* __restrict__ msg,
                                              unsigned short* __restrict__ Wkt, unsigned short* __restrict__ Wvt,
                                              float* __restrict__ bkt, float* __restrict__ bvt,
                                              int* __restrict__ cur) {
    __shared__ float sa[D * D], sm[D * D];
    int bid = blockIdx.x;
    int tid = threadIdx.x;
    if (bid < P_CVT) {
        int i = (bid * 256 + tid) * 4;
        float4 va = *(const float4*)(h_a + i);
        float4 vb = *(const float4*)(h_b + i);
        ushort4 ua = { f2bf(va.x), f2bf(va.y), f2bf(va.z), f2bf(va.w) };
        ushort4 ub = { f2bf(vb.x), f2bf(vb.y), f2bf(vb.z), f2bf(vb.w) };
        *(ushort4*)(oa + i) = ua;
        *(ushort4*)(ob + i) = ub;
        return;
    }
    bid -= P_CVT;
    if (bid < P_ZERO) {
        int i = bid * 256 + tid;
        if (i < 160000) ((int4*)cur)[i] = make_int4(0, 0, 0, 0);
        return;
    }
    bid -= P_ZERO;
    if (bid < P_PACK) {
        int n = bid;
        int t = tid >> 7, i = tid & 127;
        Wqt[(t * C + n) * C + i] = f2bf(Wq[(t * C + i) * C + n]);
        Wat[(t * C + n) * C + i] = f2bf(Wa[(t * C + i) * C + n]);
        return;
    }
    bid -= P_PACK;
    {
        int r = bid >> 3, h = bid & 7;
        int t = r >> 1;
        if (tid < D * D) {
            sa[tid] = att[(r * H + h) * D * D + tid];
            sm[tid] = msg[(r * H + h) * D * D + tid];
        }
        __syncthreads();
        int i = tid & 127;
        for (int e = (tid >> 7); e < D; e += 2) {
            float sk = 0.f, sv = 0.f;
            for (int d = 0; d < D; ++d) {
                sk += Wk[(t * C + i) * C + h * D + d] * sa[d * D + e];
                sv += Wv[(t * C + i) * C + h * D + d] * sm[d * D + e];
            }
            Wkt[(r * C + h * D + e) * C + i] = f2bf(sk);
            Wvt[(r * C + h * D + e) * C + i] = f2bf(sv);
        }
        if (tid < D) {
            int e = tid;
            float sk = 0.f, sv = 0.f;
            for (int d = 0; d < D; ++d) {
                sk += bk[t * C + h * D + d] * sa[d * D + e];
                sv += bv[t * C + h * D + d] * sm[d * D + e];
            }
            bkt[r * C + h * D + e] = sk;
            bvt[r * C + h * D + e] = sv;
        }
    }
}

// ---------------- mega: edge partition || projections, FINE-GRAINED interleave ----------------
// period 13 = 8 part + 5 proj so every CU co-hosts latency-bound part waves and
// MFMA proj waves (round-8 failure: ordered blocks never overlapped).
__global__ __launch_bounds__(256) void mega_k(const int* __restrict__ s0, const int* __restrict__ s1,
                                              const int* __restrict__ s2, const int* __restrict__ s3,
                                              const int* __restrict__ d0, const int* __restrict__ d1,
                                              const int* __restrict__ d2, const int* __restrict__ d3,
                                              int* __restrict__ cur, unsigned short* __restrict__ part,
                                              const unsigned short* __restrict__ ha,
                                              const unsigned short* __restrict__ hb,
                                              const unsigned short* __restrict__ Wqt,
                                              const unsigned short* __restrict__ Wkt,
                                              const unsigned short* __restrict__ Wvt,
                                              const float* __restrict__ bq,
                                              const float* __restrict__ bkt,
                                              const float* __restrict__ bvt,
                                              unsigned short* __restrict__ Qa,
                                              unsigned short* __restrict__ Qb,
                                              unsigned short* __restrict__ Kall,
                                              unsigned short* __restrict__ Vall) {
    int bid = blockIdx.x;
    int part_id = -1, proj_id = -1;
    if (bid < 8125) {
        int p = bid / 13, o = bid - p * 13;
        if (o < 8) part_id = p * 8 + o;
        else       proj_id = p * 5 + (o - 8);
    } else {
        proj_id = 3125 + (bid - 8125);
    }

    if (part_id >= 0) {
        // ---- partition path: 2B records, range-of-2 dsts ----
        int r = part_id / 1250;
        int eb = part_id - r * 1250;
        int e = eb * 256 + threadIdx.x;          // 1250*256 == N_EDGES
        const int* dd = (r == 0) ? d0 : (r == 1) ? d1 : (r == 2) ? d2 : d3;
        const int* ss = (r == 0) ? s0 : (r == 1) ? s1 : (r == 2) ? s2 : s3;
        int d = dd[e];
        int range = d >> 1;
        int pos = atomicAdd(&cur[(r * RANGES2 + range) * 16], 1);  // one cursor per 64B line
        if (pos < CAP2)
            part[((size_t)(r * RANGES2 + range)) * CAP2 + pos] =
                (unsigned short)(ss[e] | ((d & 1) << 15));
        return;
    }
    // ---- projection path: 10 jobs x 313 blocks ----
    int j = proj_id / 313;
    int xb = proj_id - j * 313;
    const unsigned short* A;
    const unsigned short* Wt;
    const float* bias;
    unsigned short* Out;
    if (j < 2) {
        A = j ? hb : ha; Wt = Wqt + j * C * C; bias = bq + j * C; Out = j ? Qb : Qa;
    } else if (j < 6) {
        int r = j - 2;
        A = (r < 2) ? ha : hb; Wt = Wkt + r * C * C; bias = bkt + r * C;
        Out = Kall + (size_t)r * N_NODES * C;
    } else {
        int r = j - 6;
        A = (r < 2) ? ha : hb; Wt = Wvt + r * C * C; bias = bvt + r * C;
        Out = Vall + (size_t)r * N_NODES * C;
    }
    int wid = threadIdx.x >> 6, l = threadIdx.x & 63;
    int row_base = xb * 64 + wid * 16;
    int lm = l & 15, q = l >> 4;
    f32x4 acc[8] = {};
    int arow = row_base + lm;
    if (arow >= N_NODES) arow = N_NODES - 1;
    const s16x8* Ap = (const s16x8*)(A + (size_t)arow * C);
#pragma unroll
    for (int kc = 0; kc < 4; ++kc) {
        s16x8 af = Ap[kc * 4 + q];
#pragma unroll
        for (int t = 0; t < 8; ++t) {
            s16x8 bf = *(const s16x8*)(Wt + (t * 16 + lm) * C + kc * 32 + q * 8);
            acc[t] = __builtin_amdgcn_mfma_f32_16x16x32_bf16(af, bf, acc[t], 0, 0, 0);
        }
    }
#pragma unroll
    for (int t = 0; t < 8; ++t) {
        int col = t * 16 + lm;
        float b = bias[col];
#pragma unroll
        for (int i = 0; i < 4; ++i) {
            int row = row_base + q * 4 + i;
            if (row < N_NODES) Out[(size_t)row * C + col] = f2bf(acc[t][i] + b);
        }
    }
}

// ---------------- final: out = al*(agg @ Wa + ba) + (1-al)*h ; both types via blockIdx.y ----------------
__global__ __launch_bounds__(256) void final_mm(const unsigned short* __restrict__ AggAll,
                                                const unsigned short* __restrict__ WatAll,
                                                const float* __restrict__ baAll,
                                                const float* __restrict__ skip,
                                                const float* __restrict__ h_a,
                                                const float* __restrict__ h_b,
                                                float* __restrict__ OutAll) {
    int ty = blockIdx.y;
    const unsigned short* Agg = AggAll + (size_t)ty * N_NODES * C;
    const unsigned short* Wat = WatAll + ty * C * C;
    const float* ba = baAll + ty * C;
    const float* h_orig = ty ? h_b : h_a;
    float* Out = OutAll + (size_t)ty * N_NODES * C;
    int wid = threadIdx.x >> 6, l = threadIdx.x & 63;
    int row_base = blockIdx.x * 64 + wid * 16;
    int lm = l & 15, q = l >> 4;
    f32x4 acc[8] = {};
    int arow = row_base + lm;
    if (arow >= N_NODES) arow = N_NODES - 1;
    const s16x8* Ap = (const s16x8*)(Agg + (size_t)arow * C);
#pragma unroll
    for (int kc = 0; kc < 4; ++kc) {
        s16x8 af = Ap[kc * 4 + q];
#pragma unroll
        for (int t = 0; t < 8; ++t) {
            s16x8 bf = *(const s16x8*)(Wat + (t * 16 + lm) * C + kc * 32 + q * 8);
            acc[t] = __builtin_amdgcn_mfma_f32_16x16x32_bf16(af, bf, acc[t], 0, 0, 0);
        }
    }
    float al = 1.f / (1.f + __expf(-skip[ty]));
#pragma unroll
    for (int t = 0; t < 8; ++t) {
        int col = t * 16 + lm;
        float b = ba[col];
#pragma unroll
        for (int i = 0; i < 4; ++i) {
            int row = row_base + q * 4 + i;
            if (row < N_NODES)
                Out[(size_t)row * C + col] = al * (acc[t][i] + b) + (1.f - al) * h_orig[(size_t)row * C + col];
        }
    }
}

// ---------------- P2: LDS-bin + fused scoring/softmax/aggregate ----------------
// One block per (type, 4 dsts) = two part-ranges per relation; ONE dst per wave.
__global__ __launch_bounds__(256) void node_p2(const int* __restrict__ cur,
                                               const unsigned short* __restrict__ part,
                                               const unsigned int* __restrict__ Kall,
                                               const unsigned int* __restrict__ Vall,
                                               const float* __restrict__ pri,
                                               const unsigned int* __restrict__ Qa,
                                               const unsigned int* __restrict__ Qb,
                                               unsigned int* __restrict__ agg) {
    __shared__ unsigned short slot[2][4][SLOT];
    __shared__ int cnt[2][4];
    int g = blockIdx.x;
    int type = (g >= NRANGE) ? 1 : 0;
    int range = g - type * NRANGE;     // covers nodes 4*range .. 4*range+3
    int relA = type ? 1 : 0;           // ab : aa
    int relB = type ? 3 : 2;           // bb : ba
    if (threadIdx.x < 8) ((int*)cnt)[threadIdx.x] = 0;
    __syncthreads();
#pragma unroll
    for (int rr = 0; rr < 2; ++rr) {
        int rel = rr ? relB : relA;
#pragma unroll
        for (int seg = 0; seg < 2; ++seg) {
            int r2 = range * 2 + seg;
            int c = cur[(rel * RANGES2 + r2) * 16];
            if (c > CAP2) c = CAP2;
            const unsigned short* pp = part + ((size_t)(rel * RANGES2 + r2)) * CAP2;
            for (int i = threadIdx.x; i < c; i += 256) {
                unsigned int rec = pp[i];
                int dof = 2 * seg + (rec >> 15);
                int p = atomicAdd(&cnt[rr][dof], 1);
                if (p < SLOT) slot[rr][dof][p] = (unsigned short)(rec & 0x7fffu);
            }
        }
    }
    __syncthreads();

    int wid = threadIdx.x >> 6, l = threadIdx.x & 63;
    int hg = l >> 3;
    int dof = wid;                      // ONE dst per wave
    int n = range * 4 + dof;
    const unsigned int* Q32 = type ? Qb : Qa;
    unsigned int qv = Q32[(size_t)n * 64 + l];
    float q0 = bf2f(qv & 0xffffu), q1 = bf2f(qv >> 16);
    float outx = 0.f, outy = 0.f;

#pragma unroll 1
    for (int rr = 0; rr < 2; ++rr) {
        int rel = rr ? relB : relA;
        const unsigned int* K32 = Kall + (size_t)rel * N_NODES * 64;
        const unsigned int* V32 = Vall + (size_t)rel * N_NODES * 64;
        float pv = pri[rel * 8 + hg] * 0.25f;
        int deg = cnt[rr][dof];
        if (deg > SLOT) deg = SLOT;
        float m = -1e30f, sum = 0.f;
        float ax0 = 0.f, ay0 = 0.f, ax1 = 0.f, ay1 = 0.f;
        for (int base = 0; base < deg; base += 16) {
            int cc = deg - base;
            if (cc > 16) cc = 16;
            float s[16];
            unsigned int vv[16];
#pragma unroll
            for (int i = 0; i < 16; ++i) {
                float d = -1e30f;
                unsigned int v = 0;
                if (i < cc) {
                    int sv = slot[rr][dof][base + i];   // LDS broadcast (conflict-free)
                    unsigned int kv = K32[(size_t)sv * 64 + l];
                    v = V32[(size_t)sv * 64 + l];       // fetched with K (indep of max)
                    d = q0 * bf2f(kv & 0xffffu) + q1 * bf2f(kv >> 16);
                    d += __shfl_xor(d, 1);
                    d += __shfl_xor(d, 2);
                    d += __shfl_xor(d, 4);              // full dot in all 8 lanes of head
                    d *= pv;
                }
                s[i] = d;
                vv[i] = v;
            }
            float mloc = s[0];
#pragma unroll
            for (int i = 1; i < 16; ++i) mloc = fmaxf(mloc, s[i]);
            float mnew = fmaxf(m, mloc);
            float alpha = __expf(m - mnew);             // first chunk: exp(-inf)=0
            sum *= alpha; ax0 *= alpha; ay0 *= alpha; ax1 *= alpha; ay1 *= alpha;
            m = mnew;
#pragma unroll
            for (int i = 0; i < 16; i += 2) {
                if (i < cc) {
                    float ww = __expf(s[i] - m);
                    sum += ww;
                    ax0 += ww * bf2f(vv[i] & 0xffffu);
                    ay0 += ww * bf2f(vv[i] >> 16);
                }
                if (i + 1 < cc) {
                    float ww = __expf(s[i + 1] - m);
                    sum += ww;
                    ax1 += ww * bf2f(vv[i + 1] & 0xffffu);
                    ay1 += ww * bf2f(vv[i + 1] >> 16);
                }
            }
        }
        if (deg > 0) {
            float rs = 1.f / sum;
            outx += (ax0 + ax1) * rs;
            outy += (ay0 + ay1) * rs;
        }
    }
    // 0.5 = cross_reducer 'mean'; agg stored bf16-packed
    unsigned int packed = (unsigned int)f2bf(0.5f * outx) | ((unsigned int)f2bf(0.5f * outy) << 16);
    agg[((size_t)type * N_NODES + n) * 64 + l] = packed;
}

extern "C" void kernel_launch(void* const* d_in, const int* in_sizes, int n_in,
                              void* d_out, int out_size, void* d_ws, size_t ws_size,
                              hipStream_t stream) {
    const float* h_a  = (const float*)d_in[0];
    const float* h_b  = (const float*)d_in[1];
    const float* Wk   = (const float*)d_in[2];
    const float* bk   = (const float*)d_in[3];
    const float* Wq   = (const float*)d_in[4];
    const float* bq   = (const float*)d_in[5];
    const float* Wv   = (const float*)d_in[6];
    const float* bv   = (const float*)d_in[7];
    const float* Wa   = (const float*)d_in[8];
    const float* ba   = (const float*)d_in[9];
    const float* att  = (const float*)d_in[10];
    const float* msg  = (const float*)d_in[11];
    const float* pri  = (const float*)d_in[12];
    const float* skip = (const float*)d_in[13];
    const int* srcs[4] = {(const int*)d_in[14], (const int*)d_in[16], (const int*)d_in[18], (const int*)d_in[20]};
    const int* dsts[4] = {(const int*)d_in[15], (const int*)d_in[17], (const int*)d_in[19], (const int*)d_in[21]};
    float* out = (float*)d_out;

    char* w = (char*)d_ws;
    auto alloc = [&](size_t bytes) {
        char* p = w;
        w += (bytes + 255) & ~(size_t)255;
        return p;
    };
    unsigned short* ha_bf = (unsigned short*)alloc((size_t)N_NODES * C * 2);
    unsigned short* hb_bf = (unsigned short*)alloc((size_t)N_NODES * C * 2);
    unsigned short* Qa    = (unsigned short*)alloc((size_t)N_NODES * C * 2);
    unsigned short* Qb    = (unsigned short*)alloc((size_t)N_NODES * C * 2);
    unsigned short* Kall  = (unsigned short*)alloc((size_t)4 * N_NODES * C * 2);
    unsigned short* Vall  = (unsigned short*)alloc((size_t)4 * N_NODES * C * 2);
    unsigned short* Wqt   = (unsigned short*)alloc(2 * C * C * 2);
    unsigned short* Wat   = (unsigned short*)alloc(2 * C * C * 2);
    unsigned short* Wkt   = (unsigned short*)alloc(4 * C * C * 2);
    unsigned short* Wvt   = (unsigned short*)alloc(4 * C * C * 2);
    float* bkt            = (float*)alloc(4 * C * 4);
    float* bvt            = (float*)alloc(4 * C * 4);
    int* cur              = (int*)alloc(4 * RANGES2 * 16 * 4);
    unsigned short* part  = (unsigned short*)alloc((size_t)4 * RANGES2 * CAP2 * 2);
    unsigned short* agg   = (unsigned short*)alloc((size_t)2 * N_NODES * C * 2);

    // 1) fused prep: cvt + zero-cursors + pack + fuse
    prep_k<<<P_CVT + P_ZERO + P_PACK + P_FUSE, 256, 0, stream>>>(
        h_a, h_b, ha_bf, hb_bf, Wq, Wa, Wqt, Wat,
        Wk, Wv, bk, bv, att, msg, Wkt, Wvt, bkt, bvt, cur);

    // 2) fused partition || projections (interleaved block map)
    mega_k<<<MB_TOTAL, 256, 0, stream>>>(
        srcs[0], srcs[1], srcs[2], srcs[3],
        dsts[0], dsts[1], dsts[2], dsts[3],
        cur, part,
        ha_bf, hb_bf, Wqt, Wkt, Wvt, bq, bkt, bvt,
        Qa, Qb, Kall, Vall);

    // 3) fused scoring + softmax + aggregate; 1 dst per wave
    node_p2<<<2 * NRANGE, 256, 0, stream>>>(cur, part,
                                            (const unsigned int*)Kall, (const unsigned int*)Vall,
                                            pri,
                                            (const unsigned int*)Qa, (const unsigned int*)Qb,
                                            (unsigned int*)agg);

    // 4) final skip-gated output, both types
    final_mm<<<dim3(313, 2), 256, 0, stream>>>(agg, Wat, ba, skip, h_a, h_b, out);
}